// Round 1
// 1985.458 us; speedup vs baseline: 1.2928x; 1.2928x over previous
//
#include <hip/hip_runtime.h>
#include <cstdint>
#include <cstddef>

#define NBATCH 32
#define NAGENT 100
#define NDIM   10000
#define HID    256
#define NHEAD  4
#define NOUT   10000
#define NFREQ  16
#define EMAX   100
#define NBA    3200                        // NBATCH * NAGENT
#define KBIG   25600                       // EMAX * HID
#define TWO_PI 6.283185307179586476925f

typedef float  v4f  __attribute__((ext_vector_type(4)));
typedef short  v8s  __attribute__((ext_vector_type(8)));

__device__ __forceinline__ unsigned short bf_hi(float f) {
    unsigned int u = __float_as_uint(f);
    return (unsigned short)((u + 0x7FFFu + ((u >> 16) & 1u)) >> 16);
}
__device__ __forceinline__ float bf_tof(unsigned short h) {
    return __uint_as_float(((unsigned int)h) << 16);
}

// ---------------------------------------------------------------------------
// Stage 1: per-(b,a) stream compaction of nonzeros (ascending flat index),
// truncated to EMAX. One wave per (b,a). Matches stable argsort order.
// ---------------------------------------------------------------------------
__global__ __launch_bounds__(64) void k_extract(const float* __restrict__ x,
                                                int* __restrict__ idxb,
                                                float* __restrict__ valb,
                                                int* __restrict__ nvalid)
{
    const int ba = blockIdx.x;
    const float* xr = x + (size_t)ba * NDIM;
    const int lane = threadIdx.x;
    int base = 0;
    for (int c0 = 0; c0 < NDIM; c0 += 64) {
        int i = c0 + lane;
        float v = (i < NDIM) ? xr[i] : 0.0f;
        unsigned long long m = __ballot(v != 0.0f);
        if (v != 0.0f) {
            int p = base + __popcll(m & ((1ull << lane) - 1ull));
            if (p < EMAX) {
                idxb[(size_t)ba * EMAX + p] = i;
                valb[(size_t)ba * EMAX + p] = v;
            }
        }
        base += __popcll(m);
        if (base >= EMAX) break;           // uniform across wave
    }
    if (lane == 0) nvalid[ba] = base < EMAX ? base : EMAX;
}

// ---------------------------------------------------------------------------
// Stage 2: fourier + encoder layer-1 only. g1 = swish(feat @ enc_W1^T + b1),
// zeroed for invalid slots; written as bf16 hi/lo pair (exact to ~2^-17).
// Layer-2 (enc_W2) is folded into comp_W1 algebraically (see k_tables/W1p).
// ---------------------------------------------------------------------------
__global__ __launch_bounds__(256) void k_g1(
    const int* __restrict__ idxb, const float* __restrict__ valb,
    const int* __restrict__ nvalid, const float* __restrict__ fourB,
    const float* __restrict__ W1, const float* __restrict__ b1,
    unsigned short* __restrict__ g1h, unsigned short* __restrict__ g1l)
{
    __shared__ float s_feat[16][36];
    __shared__ float s_w[8448];            // enc_W1 256x33
    __shared__ float s_b1v[256];
    __shared__ int   s_idx[16];
    __shared__ int   s_valid[16];

    const int t  = threadIdx.x;
    const int g0 = blockIdx.x * 16;

    if (t < 16) {
        int g = g0 + t;
        int ba = g / 100, slot = g - ba * 100;
        int valid = (slot < nvalid[ba]) ? 1 : 0;
        s_valid[t]   = valid;
        s_idx[t]     = valid ? idxb[g] : 0;
        s_feat[t][0] = valid ? valb[g] : 0.0f;
    }
    s_b1v[t] = b1[t];
    for (int i = t; i < 8448; i += 256) s_w[i] = W1[i];
    __syncthreads();

    {   // Fourier features: 16 entries x 16 freqs = 256 work items
        int ent = t >> 4, f = t & 15;
        float sv = 0.0f, cv = 0.0f;
        if (s_valid[ent]) {
            int id = s_idx[ent];
            float row = (float)(id / 100);
            float col = (float)(id % 100);
            float pr = TWO_PI * (row * fourB[2 * f] + col * fourB[2 * f + 1]);
            sv = sinf(pr); cv = cosf(pr);
        }
        s_feat[ent][1 + f]  = sv;
        s_feat[ent][17 + f] = cv;
    }
    __syncthreads();

    const float* wr = &s_w[t * 33];        // stride 33: conflict-free (33%32==1)
    for (int ent = 0; ent < 16; ++ent) {
        float a = s_b1v[t];
        #pragma unroll
        for (int c = 0; c < 33; ++c) a += s_feat[ent][c] * wr[c];
        float g = a / (1.0f + expf(-a));   // swish
        g = s_valid[ent] ? g : 0.0f;
        unsigned short h = bf_hi(g);
        unsigned short l = bf_hi(g - bf_tof(h));
        size_t o = (size_t)(g0 + ent) * 256 + t;
        g1h[o] = h;
        g1l[o] = l;
    }
}

// ---------------------------------------------------------------------------
// W2T[k'][k] = W2[k][k']  (tiny, 256 KB)
// ---------------------------------------------------------------------------
__global__ void k_w2t(const float* __restrict__ W2, float* __restrict__ W2T)
{
    int kp = blockIdx.x, k = threadIdx.x;
    W2T[kp * 256 + k] = W2[k * 256 + kp];
}

// ---------------------------------------------------------------------------
// fp32 -> bf16 hi/lo elementwise split (generic; total elems = grid*1024)
// ---------------------------------------------------------------------------
__global__ __launch_bounds__(256) void k_wsplit(const float* __restrict__ src,
                                                unsigned short* __restrict__ hi,
                                                unsigned short* __restrict__ lo)
{
    int i = (blockIdx.x * 256 + threadIdx.x) * 4;
    float4 f = *(const float4*)(src + i);
    ushort4 h, l;
    h.x = bf_hi(f.x); l.x = bf_hi(f.x - bf_tof(h.x));
    h.y = bf_hi(f.y); l.y = bf_hi(f.y - bf_tof(h.y));
    h.z = bf_hi(f.z); l.z = bf_hi(f.z - bf_tof(h.z));
    h.w = bf_hi(f.w); l.w = bf_hi(f.w - bf_tof(h.w));
    *(ushort4*)(hi + i) = h;
    *(ushort4*)(lo + i) = l;
}

// ---------------------------------------------------------------------------
// Bias tables for the W2-fold:
//  D[slot][n]  = (pad - b2) . comp_W1[n, slot-block]     (suffix-summed later)
//  E0[n]       = sum_slot b2 . comp_W1[n, slot-block]
// ---------------------------------------------------------------------------
__global__ __launch_bounds__(256) void k_tables(
    const float* __restrict__ W1, const float* __restrict__ pad,
    const float* __restrict__ b2, float* __restrict__ D, float* __restrict__ E0)
{
    __shared__ float red[4];
    const int n = blockIdx.x;
    const int t = threadIdx.x, lane = t & 63, w = t >> 6;
    const float pm = pad[t] - b2[t];
    const float bb = b2[t];
    const float* wr = W1 + (size_t)n * KBIG;
    float eb = 0.0f;
    for (int s = 0; s < 100; ++s) {
        float wv = wr[s * 256 + t];
        float p = pm * wv;
        eb += bb * wv;
        #pragma unroll
        for (int o = 32; o > 0; o >>= 1) p += __shfl_down(p, o);
        if (lane == 0) red[w] = p;
        __syncthreads();
        if (t == 0) D[s * 512 + n] = red[0] + red[1] + red[2] + red[3];
        __syncthreads();
    }
    #pragma unroll
    for (int o = 32; o > 0; o >>= 1) eb += __shfl_down(eb, o);
    if (lane == 0) red[w] = eb;
    __syncthreads();
    if (t == 0) E0[n] = red[0] + red[1] + red[2] + red[3];
}

__global__ void k_suffix(const float* __restrict__ D, float* __restrict__ Corr)
{
    int n = blockIdx.x * 256 + threadIdx.x;   // 512 columns
    float c = 0.0f;
    Corr[100 * 512 + n] = 0.0f;
    for (int s = 99; s >= 0; --s) { c += D[s * 512 + n]; Corr[s * 512 + n] = c; }
}

// ---------------------------------------------------------------------------
// Generic split-bf16 MFMA GEMM: C = act(A @ W^T + bias), fp32-grade accuracy
// via hi/lo compensation (3 MFMAs: hh, hl, lh). 128x128 tile, BK=32, 4 waves
// each 64x64 (4x4 of 16x16x32 MFMA). N-guard on W loads + C writes.
// LDS XOR-swizzle (idx ^ (row&7)<<3) kills the 8-way bank conflict on the
// 64B-stride fragment reads (T2, G4).
// ---------------------------------------------------------------------------
template<int ACT>
__global__ __launch_bounds__(256) void k_gemmbf(
    const unsigned short* __restrict__ Ah, const unsigned short* __restrict__ Al,
    const unsigned short* __restrict__ Wh, const unsigned short* __restrict__ Wl,
    const float* __restrict__ bias, float* __restrict__ C,
    int M, int N, int K,
    long long sA, long long sW, long long sBias, long long sC)
{
    __shared__ unsigned short sA_h[4096], sA_l[4096], sW_h[4096], sW_l[4096];
    const int t = threadIdx.x;
    const int z = blockIdx.z;
    Ah += (size_t)z * sA;  Al += (size_t)z * sA;
    Wh += (size_t)z * sW;  Wl += (size_t)z * sW;
    C  += (size_t)z * sC;
    const float* bp = bias ? (bias + (size_t)z * sBias) : nullptr;
    const int bn = blockIdx.x * 128, bm = blockIdx.y * 128;
    const int lane = t & 63, w = t >> 6;
    const int wm = (w & 1) * 64, wn = (w >> 1) * 64;
    const int r0 = t >> 2, kq = (t & 3) * 8;
    const int r1 = 64 + r0;
    const uint4 zero4 = make_uint4(0u, 0u, 0u, 0u);

    const unsigned short* pA0 = Ah + (size_t)(bm + r0) * K + kq;
    const unsigned short* pA1 = Ah + (size_t)(bm + r1) * K + kq;
    const unsigned short* pa0 = Al + (size_t)(bm + r0) * K + kq;
    const unsigned short* pa1 = Al + (size_t)(bm + r1) * K + kq;
    const bool v0 = (bn + r0) < N, v1 = (bn + r1) < N;
    const unsigned short* pW0 = Wh + (size_t)(bn + r0) * K + kq;
    const unsigned short* pW1 = Wh + (size_t)(bn + r1) * K + kq;
    const unsigned short* pw0 = Wl + (size_t)(bn + r0) * K + kq;
    const unsigned short* pw1 = Wl + (size_t)(bn + r1) * K + kq;

    uint4 rA0 = *(const uint4*)pA0, rA1 = *(const uint4*)pA1;
    uint4 ra0 = *(const uint4*)pa0, ra1 = *(const uint4*)pa1;
    uint4 rW0 = v0 ? *(const uint4*)pW0 : zero4;
    uint4 rW1 = v1 ? *(const uint4*)pW1 : zero4;
    uint4 rw0 = v0 ? *(const uint4*)pw0 : zero4;
    uint4 rw1 = v1 ? *(const uint4*)pw1 : zero4;

    v4f acc[4][4] = {};
    const int i0 = (r0 * 32 + kq) ^ ((r0 & 7) << 3);
    const int i1 = (r1 * 32 + kq) ^ ((r1 & 7) << 3);
    const int KT = K >> 5;

    for (int kt = 0; kt < KT; ++kt) {
        __syncthreads();
        *(uint4*)&sA_h[i0] = rA0;  *(uint4*)&sA_h[i1] = rA1;
        *(uint4*)&sA_l[i0] = ra0;  *(uint4*)&sA_l[i1] = ra1;
        *(uint4*)&sW_h[i0] = rW0;  *(uint4*)&sW_h[i1] = rW1;
        *(uint4*)&sW_l[i0] = rw0;  *(uint4*)&sW_l[i1] = rw1;
        __syncthreads();
        if (kt + 1 < KT) {
            int o = (kt + 1) * 32;
            rA0 = *(const uint4*)(pA0 + o);  rA1 = *(const uint4*)(pA1 + o);
            ra0 = *(const uint4*)(pa0 + o);  ra1 = *(const uint4*)(pa1 + o);
            rW0 = v0 ? *(const uint4*)(pW0 + o) : zero4;
            rW1 = v1 ? *(const uint4*)(pW1 + o) : zero4;
            rw0 = v0 ? *(const uint4*)(pw0 + o) : zero4;
            rw1 = v1 ? *(const uint4*)(pw1 + o) : zero4;
        }
        const int fr = lane & 15, fq = (lane >> 4) * 8;
        v8s ahf[4], alf[4], bhf[4], blf[4];
        #pragma unroll
        for (int i = 0; i < 4; ++i) {
            int ar = wm + i * 16 + fr;
            int br = wn + i * 16 + fr;
            int ai = (ar * 32 + fq) ^ ((ar & 7) << 3);
            int bi = (br * 32 + fq) ^ ((br & 7) << 3);
            ahf[i] = *(const v8s*)&sA_h[ai];
            alf[i] = *(const v8s*)&sA_l[ai];
            bhf[i] = *(const v8s*)&sW_h[bi];
            blf[i] = *(const v8s*)&sW_l[bi];
        }
        #pragma unroll
        for (int mi = 0; mi < 4; ++mi)
            #pragma unroll
            for (int ni = 0; ni < 4; ++ni) {
                acc[mi][ni] = __builtin_amdgcn_mfma_f32_16x16x32_bf16(ahf[mi], bhf[ni], acc[mi][ni], 0, 0, 0);
                acc[mi][ni] = __builtin_amdgcn_mfma_f32_16x16x32_bf16(ahf[mi], blf[ni], acc[mi][ni], 0, 0, 0);
                acc[mi][ni] = __builtin_amdgcn_mfma_f32_16x16x32_bf16(alf[mi], bhf[ni], acc[mi][ni], 0, 0, 0);
            }
    }

    const int er = (lane >> 4) * 4, ec = lane & 15;  // C/D: col=lane&15, row=quad*4+reg
    #pragma unroll
    for (int mi = 0; mi < 4; ++mi)
        #pragma unroll
        for (int ni = 0; ni < 4; ++ni) {
            int m = bm + wm + mi * 16 + er;
            int n = bn + wn + ni * 16 + ec;
            if (n < N) {
                float bv = bp ? bp[n] : 0.0f;
                #pragma unroll
                for (int r = 0; r < 4; ++r) {
                    float val = acc[mi][ni][r] + bv;
                    if (ACT == 1) val = val / (1.0f + expf(-val));   // swish
                    C[(size_t)(m + r) * N + n] = val;
                }
            }
        }
    (void)M;
}

// ---------------------------------------------------------------------------
// Compression GEMM via bf16 MFMA with hi/lo split, split-K=8.
// Same structure as before + LDS XOR-swizzle on stores/fragment-reads.
// ---------------------------------------------------------------------------
__global__ __launch_bounds__(256) void k_g3mfma(
    const unsigned short* __restrict__ Ah, const unsigned short* __restrict__ Al,
    const unsigned short* __restrict__ Wh, const unsigned short* __restrict__ Wl,
    float* __restrict__ part)
{
    __shared__ unsigned short sAh[4096], sAl[4096], sWh[4096], sWl[4096];
    const int t  = threadIdx.x;
    const int bn = blockIdx.x * 128;       // N in [0,512)
    const int bm = blockIdx.y * 128;       // M in [0,3200)
    const int z  = blockIdx.z;             // split-K chunk, 8 x 3200
    const int lane = t & 63, w = t >> 6;
    const int wm = (w & 1) * 64, wn = (w >> 1) * 64;
    const size_t K = KBIG;
    const int r0 = t >> 2, kq = (t & 3) * 8;
    const int r1 = 64 + r0;

    const unsigned short* pA0 = Ah + (size_t)(bm + r0) * K + z * 3200 + kq;
    const unsigned short* pA1 = Ah + (size_t)(bm + r1) * K + z * 3200 + kq;
    const unsigned short* pa0 = Al + (size_t)(bm + r0) * K + z * 3200 + kq;
    const unsigned short* pa1 = Al + (size_t)(bm + r1) * K + z * 3200 + kq;
    const unsigned short* pW0 = Wh + (size_t)(bn + r0) * K + z * 3200 + kq;
    const unsigned short* pW1 = Wh + (size_t)(bn + r1) * K + z * 3200 + kq;
    const unsigned short* pw0 = Wl + (size_t)(bn + r0) * K + z * 3200 + kq;
    const unsigned short* pw1 = Wl + (size_t)(bn + r1) * K + z * 3200 + kq;

    uint4 rA0 = *(const uint4*)pA0, rA1 = *(const uint4*)pA1;
    uint4 ra0 = *(const uint4*)pa0, ra1 = *(const uint4*)pa1;
    uint4 rW0 = *(const uint4*)pW0, rW1 = *(const uint4*)pW1;
    uint4 rw0 = *(const uint4*)pw0, rw1 = *(const uint4*)pw1;

    v4f acc[4][4] = {};
    const int i0 = (r0 * 32 + kq) ^ ((r0 & 7) << 3);
    const int i1 = (r1 * 32 + kq) ^ ((r1 & 7) << 3);

    for (int kt = 0; kt < 100; ++kt) {
        __syncthreads();
        *(uint4*)&sAh[i0] = rA0;  *(uint4*)&sAh[i1] = rA1;
        *(uint4*)&sAl[i0] = ra0;  *(uint4*)&sAl[i1] = ra1;
        *(uint4*)&sWh[i0] = rW0;  *(uint4*)&sWh[i1] = rW1;
        *(uint4*)&sWl[i0] = rw0;  *(uint4*)&sWl[i1] = rw1;
        __syncthreads();
        if (kt < 99) {
            int off = (kt + 1) * 32;
            rA0 = *(const uint4*)(pA0 + off);  rA1 = *(const uint4*)(pA1 + off);
            ra0 = *(const uint4*)(pa0 + off);  ra1 = *(const uint4*)(pa1 + off);
            rW0 = *(const uint4*)(pW0 + off);  rW1 = *(const uint4*)(pW1 + off);
            rw0 = *(const uint4*)(pw0 + off);  rw1 = *(const uint4*)(pw1 + off);
        }
        const int fr = lane & 15, fq = (lane >> 4) * 8;
        v8s ah[4], al[4], bh[4], bl[4];
        #pragma unroll
        for (int i = 0; i < 4; ++i) {
            int ar = wm + i * 16 + fr;
            int br = wn + i * 16 + fr;
            int ai = (ar * 32 + fq) ^ ((ar & 7) << 3);
            int bi = (br * 32 + fq) ^ ((br & 7) << 3);
            ah[i] = *(const v8s*)&sAh[ai];
            al[i] = *(const v8s*)&sAl[ai];
            bh[i] = *(const v8s*)&sWh[bi];
            bl[i] = *(const v8s*)&sWl[bi];
        }
        #pragma unroll
        for (int mi = 0; mi < 4; ++mi)
            #pragma unroll
            for (int ni = 0; ni < 4; ++ni) {
                acc[mi][ni] = __builtin_amdgcn_mfma_f32_16x16x32_bf16(ah[mi], bh[ni], acc[mi][ni], 0, 0, 0);
                acc[mi][ni] = __builtin_amdgcn_mfma_f32_16x16x32_bf16(ah[mi], bl[ni], acc[mi][ni], 0, 0, 0);
                acc[mi][ni] = __builtin_amdgcn_mfma_f32_16x16x32_bf16(al[mi], bh[ni], acc[mi][ni], 0, 0, 0);
            }
    }

    const int er = (lane >> 4) * 4, ec = lane & 15;
    float* cp = part + (size_t)z * NBA * 512;
    #pragma unroll
    for (int mi = 0; mi < 4; ++mi)
        #pragma unroll
        for (int ni = 0; ni < 4; ++ni) {
            int m = bm + wm + mi * 16 + er;
            int n = bn + wn + ni * 16 + ec;
            #pragma unroll
            for (int r = 0; r < 4; ++r)
                cp[(size_t)(m + r) * 512 + n] = acc[mi][ni][r];
        }
}

// ---------------------------------------------------------------------------
// Split-K reduce + fold-bias + swish, emitting bf16 hi/lo directly:
// h1s = swish(sum_z part + comp_b1 + E0 + Corr[nvalid[ba]])
// ---------------------------------------------------------------------------
__global__ __launch_bounds__(256) void k_g3red(
    const float* __restrict__ part, const float* __restrict__ comp_b1,
    const float* __restrict__ E0, const float* __restrict__ Corr,
    const int* __restrict__ nvalid,
    unsigned short* __restrict__ oh, unsigned short* __restrict__ ol)
{
    const int i4 = (blockIdx.x * 256 + threadIdx.x) * 4;
    const int ba = i4 >> 9, n = i4 & 511;
    const size_t S = (size_t)NBA * 512;
    float4 s = *(const float4*)(part + i4);
    #pragma unroll
    for (int zz = 1; zz < 8; ++zz) {
        float4 p = *(const float4*)(part + zz * S + i4);
        s.x += p.x; s.y += p.y; s.z += p.z; s.w += p.w;
    }
    int nv = nvalid[ba];
    float4 b  = *(const float4*)(comp_b1 + n);
    float4 e  = *(const float4*)(E0 + n);
    float4 c  = *(const float4*)(Corr + nv * 512 + n);
    float r0 = s.x + b.x + e.x + c.x;
    float r1 = s.y + b.y + e.y + c.y;
    float r2 = s.z + b.z + e.z + c.z;
    float r3 = s.w + b.w + e.w + c.w;
    float4 o;
    o.x = r0 / (1.0f + expf(-r0));
    o.y = r1 / (1.0f + expf(-r1));
    o.z = r2 / (1.0f + expf(-r2));
    o.w = r3 / (1.0f + expf(-r3));
    ushort4 h, l;
    h.x = bf_hi(o.x); l.x = bf_hi(o.x - bf_tof(h.x));
    h.y = bf_hi(o.y); l.y = bf_hi(o.y - bf_tof(h.y));
    h.z = bf_hi(o.z); l.z = bf_hi(o.z - bf_tof(h.z));
    h.w = bf_hi(o.w); l.w = bf_hi(o.w - bf_tof(h.w));
    *(ushort4*)(oh + i4) = h;
    *(ushort4*)(ol + i4) = l;
}

// ---------------------------------------------------------------------------
// Fused attention (unchanged; output buffer aliases Qb — each block
// reads only its own half's Q rows before writing those same rows).
// ---------------------------------------------------------------------------
__global__ __launch_bounds__(256) void k_attn(
    const float* __restrict__ Qb, const float* __restrict__ Kb,
    const float* __restrict__ Vb, const float* __restrict__ conn,
    float* __restrict__ sHm)
{
    __shared__ float sKV[256][101];
    __shared__ float sAl[50][100];
    __shared__ float sQ[2][256];
    __shared__ float sRed[2][2];

    const int t = threadIdx.x;
    const int half = blockIdx.x, b = blockIdx.y, n = blockIdx.z;
    const size_t base = ((size_t)n * NBA + b * 100) * 256;

    const float* Kp = Kb + base;
    for (int r = 0; r < 100; ++r) sKV[t][r] = Kp[(size_t)r * 256 + t];
    __syncthreads();

    const float* Qp = Qb + base;
    const int pair = t >> 7, tt = t & 127, lane = t & 63, wvi = t >> 6;

    for (int rr = 0; rr < 25; ++rr) {
        const int row0 = half * 50 + rr * 2;
        const int lr = rr * 2 + pair;
        __syncthreads();
        sQ[0][t] = Qp[(size_t)(row0)*256 + t];
        sQ[1][t] = Qp[(size_t)(row0 + 1) * 256 + t];
        __syncthreads();
        float sc = 0.0f;
        if (tt < 100) {
            const float* qr = sQ[pair];
            float p0 = 0.f, p1 = 0.f, p2 = 0.f, p3 = 0.f;
            #pragma unroll 4
            for (int c = 0; c < 256; c += 4) {
                p0 += qr[c]     * sKV[c][tt];
                p1 += qr[c + 1] * sKV[c + 1][tt];
                p2 += qr[c + 2] * sKV[c + 2][tt];
                p3 += qr[c + 3] * sKV[c + 3][tt];
            }
            sc = ((p0 + p1) + (p2 + p3)) * 0.0625f + conn[(row0 + pair) * 100 + tt];
            sAl[lr][tt] = sc;
        }
        __syncthreads();
        if ((wvi & 1) == 0) {
            int p = wvi >> 1;
            int r2 = rr * 2 + p;
            float m = sAl[r2][lane];
            if (lane < 36) m = fmaxf(m, sAl[r2][lane + 64]);
            #pragma unroll
            for (int off = 32; off > 0; off >>= 1)
                m = fmaxf(m, __shfl_down(m, off));
            if (lane == 0) sRed[0][p] = m;
        }
        __syncthreads();
        float ex = 0.0f;
        if (tt < 100) {
            ex = expf(sc - sRed[0][pair]);
            sAl[lr][tt] = ex;
        }
        __syncthreads();
        if ((wvi & 1) == 0) {
            int p = wvi >> 1;
            int r2 = rr * 2 + p;
            float s = sAl[r2][lane];
            if (lane < 36) s += sAl[r2][lane + 64];
            #pragma unroll
            for (int off = 32; off > 0; off >>= 1)
                s += __shfl_down(s, off);
            if (lane == 0) sRed[1][p] = s;
        }
        __syncthreads();
        if (tt < 100) sAl[lr][tt] = ex / sRed[1][pair];
    }
    __syncthreads();

    const float* Vp = Vb + base;
    for (int r = 0; r < 100; ++r) sKV[t][r] = Vp[(size_t)r * 256 + t];
    __syncthreads();

    float* Op = sHm + base;
    for (int rr = 0; rr < 50; ++rr) {
        int row = half * 50 + rr;
        float a = 0.0f;
        #pragma unroll 4
        for (int j = 0; j < 100; ++j) a += sAl[rr][j] * sKV[t][j];
        float sw = a / (1.0f + expf(-a));   // swish fused (fp1 consumes swish(Hm))
        Op[(size_t)row * 256 + t] = sw;
    }
}

// ---------------------------------------------------------------------------
// Per-head layernorm over HID + mean over heads -> new h, emitted directly
// as bf16 hi/lo split (all consumers are MFMA GEMMs).
// ---------------------------------------------------------------------------
__global__ __launch_bounds__(256) void k_ln_mean(
    const float* __restrict__ t2b, const float* __restrict__ ln_g,
    const float* __restrict__ ln_b,
    unsigned short* __restrict__ hh, unsigned short* __restrict__ hl)
{
    __shared__ float so[4][256];
    const int ba = blockIdx.x, t = threadIdx.x;
    const int n = t >> 6, lane = t & 63;
    const float* tr = t2b + ((size_t)n * NBA + ba) * HID;
    float4 v = *(const float4*)(tr + lane * 4);
    float s1 = v.x + v.y + v.z + v.w;
    float s2 = v.x * v.x + v.y * v.y + v.z * v.z + v.w * v.w;
    #pragma unroll
    for (int off = 32; off > 0; off >>= 1) {
        s1 += __shfl_down(s1, off);
        s2 += __shfl_down(s2, off);
    }
    s1 = __shfl(s1, 0);
    s2 = __shfl(s2, 0);
    float m = s1 * (1.0f / 256.0f);
    float var = s2 * (1.0f / 256.0f) - m * m;
    float rstd = 1.0f / sqrtf(var + 1e-5f);
    float4 gv = *(const float4*)(ln_g + n * HID + lane * 4);
    float4 bv = *(const float4*)(ln_b + n * HID + lane * 4);
    float4 o;
    o.x = (v.x - m) * rstd * gv.x + bv.x;
    o.y = (v.y - m) * rstd * gv.y + bv.y;
    o.z = (v.z - m) * rstd * gv.z + bv.z;
    o.w = (v.w - m) * rstd * gv.w + bv.w;
    *(float4*)&so[n][lane * 4] = o;
    __syncthreads();
    float hv = 0.25f * (so[0][t] + so[1][t] + so[2][t] + so[3][t]);
    unsigned short hi = bf_hi(hv);
    size_t oidx = (size_t)ba * HID + t;
    hh[oidx] = hi;
    hl[oidx] = bf_hi(hv - bf_tof(hi));
}

// ---------------------------------------------------------------------------
extern "C" void kernel_launch(void* const* d_in, const int* in_sizes, int n_in,
                              void* d_out, int out_size, void* d_ws, size_t ws_size,
                              hipStream_t stream)
{
    const float* x       = (const float*)d_in[0];
    const float* fourB   = (const float*)d_in[1];
    const float* enc_W1  = (const float*)d_in[2];
    const float* enc_b1  = (const float*)d_in[3];
    const float* enc_W2  = (const float*)d_in[4];
    const float* enc_b2  = (const float*)d_in[5];
    const float* pad_tok = (const float*)d_in[6];
    const float* comp_W1 = (const float*)d_in[7];
    const float* comp_b1 = (const float*)d_in[8];
    const float* comp_W2 = (const float*)d_in[9];
    const float* comp_b2 = (const float*)d_in[10];
    const float* conn    = (const float*)d_in[11];
    const float* qW      = (const float*)d_in[12];
    const float* kW      = (const float*)d_in[13];
    const float* vW      = (const float*)d_in[14];
    const float* fpW1    = (const float*)d_in[15];
    const float* fpb1    = (const float*)d_in[16];
    const float* fpW2    = (const float*)d_in[17];
    const float* fpb2    = (const float*)d_in[18];
    const float* ln_g    = (const float*)d_in[19];
    const float* ln_b    = (const float*)d_in[20];
    const float* out_W   = (const float*)d_in[21];
    const float* out_b   = (const float*)d_in[22];
    float* outp = (float*)d_out;

    char* ws = (char*)d_ws;
    size_t off = 0;
    auto alloc = [&](size_t bytes) -> void* {
        void* p = (void*)(ws + off);
        off += (bytes + 255) & ~(size_t)255;
        return p;
    };
    int*   idxb = (int*)  alloc((size_t)NBA * EMAX * 4);
    float* valb = (float*)alloc((size_t)NBA * EMAX * 4);
    int*   nval = (int*)  alloc((size_t)NBA * 4);
    unsigned short* g1h = (unsigned short*)alloc((size_t)NBA * KBIG * 2);  // 163.8 MB
    unsigned short* g1l = (unsigned short*)alloc((size_t)NBA * KBIG * 2);  // 163.8 MB
    float* W2T  = (float*)alloc((size_t)256 * 256 * 4);
    float* W1p  = (float*)alloc((size_t)512 * KBIG * 4);     // 52.4 MB; reused as split-K partials
    float* part = W1p;                                       // alias (W1p dead after k_wsplit)
    unsigned short* Whi = (unsigned short*)alloc((size_t)512 * KBIG * 2);
    unsigned short* Wlo = (unsigned short*)alloc((size_t)512 * KBIG * 2);
    float* Dt   = (float*)alloc((size_t)100 * 512 * 4);
    float* Corr = (float*)alloc((size_t)101 * 512 * 4);
    float* E0   = (float*)alloc((size_t)512 * 4);
    float* h    = (float*)alloc((size_t)NBA * HID * 4);
    // --- contiguous region: Qb | Kb | Vb | asplh | aspll  (52,428,800 B) ---
    // Also aliased (earlier in the stream) as cW1h/cW1l: the bf16 hi/lo split
    // of comp_W1 (13,107,200 elems each = 26.2 MB each), dead after the fold.
    float* Qb   = (float*)alloc((size_t)NHEAD * NBA * HID * 4);   // 13,107,200 B
    float* Kb   = (float*)alloc((size_t)NHEAD * NBA * HID * 4);
    float* Vb   = (float*)alloc((size_t)NHEAD * NBA * HID * 4);
    unsigned short* asplh = (unsigned short*)alloc((size_t)NHEAD * NBA * HID * 2); // 6.55 MB
    unsigned short* aspll = (unsigned short*)alloc((size_t)NHEAD * NBA * HID * 2);
    unsigned short* cW1h = (unsigned short*)Qb;   // spans Qb+Kb
    unsigned short* cW1l = (unsigned short*)Vb;   // spans Vb+asplh+aspll
    // weight splits (persistent through the call)
    unsigned short* w2tH = (unsigned short*)alloc((size_t)256 * 256 * 2);
    unsigned short* w2tL = (unsigned short*)alloc((size_t)256 * 256 * 2);
    unsigned short* qkvWh = (unsigned short*)alloc((size_t)3 * NHEAD * HID * HID * 2);
    unsigned short* qkvWl = (unsigned short*)alloc((size_t)3 * NHEAD * HID * HID * 2);
    unsigned short* f1Wh = (unsigned short*)alloc((size_t)NHEAD * HID * HID * 2);
    unsigned short* f1Wl = (unsigned short*)alloc((size_t)NHEAD * HID * HID * 2);
    unsigned short* f2Wh = (unsigned short*)alloc((size_t)NHEAD * HID * HID * 2);
    unsigned short* f2Wl = (unsigned short*)alloc((size_t)NHEAD * HID * HID * 2);
    unsigned short* c2Wh = (unsigned short*)alloc((size_t)HID * 512 * 2);
    unsigned short* c2Wl = (unsigned short*)alloc((size_t)HID * 512 * 2);
    unsigned short* oWh  = (unsigned short*)alloc((size_t)NOUT * HID * 2);
    unsigned short* oWl  = (unsigned short*)alloc((size_t)NOUT * HID * 2);
    // aliases (lifetimes disjoint within a step)
    float* sHmB = Qb;   // attn writes its own half's rows after reading them
    float* t1s  = Kb;   // K dead after attn
    float* t2b  = Vb;   // V dead after attn

    const long long sW = (long long)HID * HID;   // 65536
    const long long sC = (long long)NBA * HID;   // 819200

    k_extract<<<NBA, 64, 0, stream>>>(x, idxb, valb, nval);
    k_g1<<<NBA * EMAX / 16, 256, 0, stream>>>(idxb, valb, nval, fourB,
                                              enc_W1, enc_b1, g1h, g1l);

    // fold enc_W2 into comp_W1:  W1p[(n,slot)][k'] = sum_k W1[n,slot,k]*W2[k][k']
    // now done in split-bf16 MFMA (A = comp_W1 split, W = W2T split).
    k_w2t<<<256, 256, 0, stream>>>(enc_W2, W2T);
    k_wsplit<<<256 * 256 / 1024, 256, 0, stream>>>(W2T, w2tH, w2tL);
    k_wsplit<<<512 * KBIG / 1024, 256, 0, stream>>>(comp_W1, cW1h, cW1l);
    k_gemmbf<0><<<dim3(2, 400, 1), 256, 0, stream>>>(
        cW1h, cW1l, w2tH, w2tL, nullptr, W1p, 512 * EMAX, 256, 256, 0, 0, 0, 0);
    k_wsplit<<<512 * KBIG / 1024, 256, 0, stream>>>(W1p, Whi, Wlo);
    k_tables<<<512, 256, 0, stream>>>(comp_W1, pad_tok, enc_b2, Dt, E0);
    k_suffix<<<2, 256, 0, stream>>>(Dt, Corr);

    // one-time weight splits (replaces the QKV concat memcpys)
    k_wsplit<<<NHEAD * 65536 / 1024, 256, 0, stream>>>(qW, qkvWh, qkvWl);
    k_wsplit<<<NHEAD * 65536 / 1024, 256, 0, stream>>>(kW, qkvWh + NHEAD * 65536, qkvWl + NHEAD * 65536);
    k_wsplit<<<NHEAD * 65536 / 1024, 256, 0, stream>>>(vW, qkvWh + 2 * NHEAD * 65536, qkvWl + 2 * NHEAD * 65536);
    k_wsplit<<<NHEAD * 65536 / 1024, 256, 0, stream>>>(fpW1, f1Wh, f1Wl);
    k_wsplit<<<NHEAD * 65536 / 1024, 256, 0, stream>>>(fpW2, f2Wh, f2Wl);
    k_wsplit<<<HID * 512 / 1024, 256, 0, stream>>>(comp_W2, c2Wh, c2Wl);
    k_wsplit<<<NOUT * HID / 1024, 256, 0, stream>>>(out_W, oWh, oWl);

    // compression GEMM (M=3200,N=512,K=25600) in split-bf16 MFMA, split-K=8
    k_g3mfma<<<dim3(4, 25, 8), 256, 0, stream>>>(g1h, g1l, Whi, Wlo, part);
    // reduce + bias-fold + swish, emits h1s-split directly into aspl
    k_g3red<<<NBA * 512 / 1024, 256, 0, stream>>>(part, comp_b1, E0, Corr, nval, asplh, aspll);
    // h = h1s @ comp_W2^T + b2   (M=3200, N=256, K=512)
    k_gemmbf<0><<<dim3(2, 25, 1), 256, 0, stream>>>(
        asplh, aspll, c2Wh, c2Wl, comp_b2, h, NBA, HID, 512, 0, 0, 0, 0);
    k_wsplit<<<NBA * HID / 1024, 256, 0, stream>>>(h, asplh, aspll);

    for (int step = 0; step < 3; ++step) {
        // QKV: 12-batched (4 Q heads, 4 K heads, 4 V heads)
        k_gemmbf<0><<<dim3(2, 25, 12), 256, 0, stream>>>(
            asplh, aspll, qkvWh, qkvWl, nullptr, Qb, NBA, HID, HID, 0, sW, 0, sC);
        k_attn<<<dim3(2, NBATCH, NHEAD), 256, 0, stream>>>(Qb, Kb, Vb, conn, sHmB);
        k_wsplit<<<NHEAD * NBA * HID / 1024, 256, 0, stream>>>(sHmB, asplh, aspll);
        k_gemmbf<1><<<dim3(2, 25, 4), 256, 0, stream>>>(
            asplh, aspll, f1Wh, f1Wl, fpb1, t1s, NBA, HID, HID, sC, sW, HID, sC);
        k_wsplit<<<NHEAD * NBA * HID / 1024, 256, 0, stream>>>(t1s, asplh, aspll);
        k_gemmbf<0><<<dim3(2, 25, 4), 256, 0, stream>>>(
            asplh, aspll, f2Wh, f2Wl, fpb2, t2b, NBA, HID, HID, sC, sW, HID, sC);
        // layernorm + head-mean, emits next h as hi/lo split into aspl
        k_ln_mean<<<NBA, 256, 0, stream>>>(t2b, ln_g, ln_b, asplh, aspll);
    }

    // out = h @ out_W^T + out_b  (M=3200, N=10000, K=256)
    k_gemmbf<0><<<dim3(79, 25, 1), 256, 0, stream>>>(
        asplh, aspll, oWh, oWl, out_b, outp, NBA, NOUT, HID, 0, 0, 0, 0);

    (void)in_sizes; (void)n_in; (void)out_size; (void)ws_size;
}

// Round 4
// 1904.932 us; speedup vs baseline: 1.3474x; 1.0423x over previous
//
#include <hip/hip_runtime.h>
#include <cstdint>
#include <cstddef>

#define NBATCH 32
#define NAGENT 100
#define NDIM   10000
#define HID    256
#define NHEAD  4
#define NOUT   10000
#define NFREQ  16
#define EMAX   100
#define NBA    3200                        // NBATCH * NAGENT
#define KBIG   25600                       // EMAX * HID
#define TWO_PI 6.283185307179586476925f

typedef float  v4f  __attribute__((ext_vector_type(4)));
typedef short  v8s  __attribute__((ext_vector_type(8)));

__device__ __forceinline__ unsigned short bf_hi(float f) {
    unsigned int u = __float_as_uint(f);
    return (unsigned short)((u + 0x7FFFu + ((u >> 16) & 1u)) >> 16);
}
__device__ __forceinline__ float bf_tof(unsigned short h) {
    return __uint_as_float(((unsigned int)h) << 16);
}

// ---------------------------------------------------------------------------
// Stage 1: per-(b,a) stream compaction of nonzeros (ascending flat index),
// truncated to EMAX. One wave per (b,a). Matches stable argsort order.
// ---------------------------------------------------------------------------
__global__ __launch_bounds__(64) void k_extract(const float* __restrict__ x,
                                                int* __restrict__ idxb,
                                                float* __restrict__ valb,
                                                int* __restrict__ nvalid)
{
    const int ba = blockIdx.x;
    const float* xr = x + (size_t)ba * NDIM;
    const int lane = threadIdx.x;
    int base = 0;
    for (int c0 = 0; c0 < NDIM; c0 += 64) {
        int i = c0 + lane;
        float v = (i < NDIM) ? xr[i] : 0.0f;
        unsigned long long m = __ballot(v != 0.0f);
        if (v != 0.0f) {
            int p = base + __popcll(m & ((1ull << lane) - 1ull));
            if (p < EMAX) {
                idxb[(size_t)ba * EMAX + p] = i;
                valb[(size_t)ba * EMAX + p] = v;
            }
        }
        base += __popcll(m);
        if (base >= EMAX) break;           // uniform across wave
    }
    if (lane == 0) nvalid[ba] = base < EMAX ? base : EMAX;
}

// ---------------------------------------------------------------------------
// Stage 2: fourier + encoder layer-1 only. g1 = swish(feat @ enc_W1^T + b1),
// zeroed for invalid slots; written as bf16 hi/lo pair (exact to ~2^-17).
// ---------------------------------------------------------------------------
__global__ __launch_bounds__(256) void k_g1(
    const int* __restrict__ idxb, const float* __restrict__ valb,
    const int* __restrict__ nvalid, const float* __restrict__ fourB,
    const float* __restrict__ W1, const float* __restrict__ b1,
    unsigned short* __restrict__ g1h, unsigned short* __restrict__ g1l)
{
    __shared__ float s_feat[16][36];
    __shared__ float s_w[8448];            // enc_W1 256x33
    __shared__ float s_b1v[256];
    __shared__ int   s_idx[16];
    __shared__ int   s_valid[16];

    const int t  = threadIdx.x;
    const int g0 = blockIdx.x * 16;

    if (t < 16) {
        int g = g0 + t;
        int ba = g / 100, slot = g - ba * 100;
        int valid = (slot < nvalid[ba]) ? 1 : 0;
        s_valid[t]   = valid;
        s_idx[t]     = valid ? idxb[g] : 0;
        s_feat[t][0] = valid ? valb[g] : 0.0f;
    }
    s_b1v[t] = b1[t];
    for (int i = t; i < 8448; i += 256) s_w[i] = W1[i];
    __syncthreads();

    {   // Fourier features: 16 entries x 16 freqs = 256 work items
        int ent = t >> 4, f = t & 15;
        float sv = 0.0f, cv = 0.0f;
        if (s_valid[ent]) {
            int id = s_idx[ent];
            float row = (float)(id / 100);
            float col = (float)(id % 100);
            float pr = TWO_PI * (row * fourB[2 * f] + col * fourB[2 * f + 1]);
            sv = sinf(pr); cv = cosf(pr);
        }
        s_feat[ent][1 + f]  = sv;
        s_feat[ent][17 + f] = cv;
    }
    __syncthreads();

    const float* wr = &s_w[t * 33];        // stride 33: conflict-free (33%32==1)
    for (int ent = 0; ent < 16; ++ent) {
        float a = s_b1v[t];
        #pragma unroll
        for (int c = 0; c < 33; ++c) a += s_feat[ent][c] * wr[c];
        float g = a / (1.0f + expf(-a));   // swish
        g = s_valid[ent] ? g : 0.0f;
        unsigned short h = bf_hi(g);
        unsigned short l = bf_hi(g - bf_tof(h));
        size_t o = (size_t)(g0 + ent) * 256 + t;
        g1h[o] = h;
        g1l[o] = l;
    }
}

// ---------------------------------------------------------------------------
// W2T[k'][k] = W2[k][k']  (tiny, 256 KB)
// ---------------------------------------------------------------------------
__global__ void k_w2t(const float* __restrict__ W2, float* __restrict__ W2T)
{
    int kp = blockIdx.x, k = threadIdx.x;
    W2T[kp * 256 + k] = W2[k * 256 + kp];
}

// ---------------------------------------------------------------------------
// fp32 -> bf16 hi/lo elementwise split (generic; total elems = grid*1024)
// ---------------------------------------------------------------------------
__global__ __launch_bounds__(256) void k_wsplit(const float* __restrict__ src,
                                                unsigned short* __restrict__ hi,
                                                unsigned short* __restrict__ lo)
{
    int i = (blockIdx.x * 256 + threadIdx.x) * 4;
    float4 f = *(const float4*)(src + i);
    ushort4 h, l;
    h.x = bf_hi(f.x); l.x = bf_hi(f.x - bf_tof(h.x));
    h.y = bf_hi(f.y); l.y = bf_hi(f.y - bf_tof(h.y));
    h.z = bf_hi(f.z); l.z = bf_hi(f.z - bf_tof(h.z));
    h.w = bf_hi(f.w); l.w = bf_hi(f.w - bf_tof(h.w));
    *(ushort4*)(hi + i) = h;
    *(ushort4*)(lo + i) = l;
}

// ---------------------------------------------------------------------------
// Bias tables for the W2-fold.
// ---------------------------------------------------------------------------
__global__ __launch_bounds__(256) void k_tables(
    const float* __restrict__ W1, const float* __restrict__ pad,
    const float* __restrict__ b2, float* __restrict__ D, float* __restrict__ E0)
{
    __shared__ float red[4];
    const int n = blockIdx.x;
    const int t = threadIdx.x, lane = t & 63, w = t >> 6;
    const float pm = pad[t] - b2[t];
    const float bb = b2[t];
    const float* wr = W1 + (size_t)n * KBIG;
    float eb = 0.0f;
    for (int s = 0; s < 100; ++s) {
        float wv = wr[s * 256 + t];
        float p = pm * wv;
        eb += bb * wv;
        #pragma unroll
        for (int o = 32; o > 0; o >>= 1) p += __shfl_down(p, o);
        if (lane == 0) red[w] = p;
        __syncthreads();
        if (t == 0) D[s * 512 + n] = red[0] + red[1] + red[2] + red[3];
        __syncthreads();
    }
    #pragma unroll
    for (int o = 32; o > 0; o >>= 1) eb += __shfl_down(eb, o);
    if (lane == 0) red[w] = eb;
    __syncthreads();
    if (t == 0) E0[n] = red[0] + red[1] + red[2] + red[3];
}

__global__ void k_suffix(const float* __restrict__ D, float* __restrict__ Corr)
{
    int n = blockIdx.x * 256 + threadIdx.x;   // 512 columns
    float c = 0.0f;
    Corr[100 * 512 + n] = 0.0f;
    for (int s = 99; s >= 0; --s) { c += D[s * 512 + n]; Corr[s * 512 + n] = c; }
}

// ---------------------------------------------------------------------------
// Generic split-bf16 MFMA GEMM: C = act(A @ W^T + bias), fp32-grade accuracy
// via hi/lo compensation (3 MFMAs: hh, hl, lh). 128x128 tile, BK=32, 4 waves
// each 64x64 (4x4 of 16x16x32 MFMA). N-guard on W loads + C writes.
// SPLIT=1: emit bf16 hi/lo (Ch/Cl) instead of fp32 C.
// ---------------------------------------------------------------------------
template<int ACT, int SPLIT>
__global__ __launch_bounds__(256) void k_gemmbf(
    const unsigned short* __restrict__ Ah, const unsigned short* __restrict__ Al,
    const unsigned short* __restrict__ Wh, const unsigned short* __restrict__ Wl,
    const float* __restrict__ bias, float* __restrict__ C,
    unsigned short* __restrict__ Ch, unsigned short* __restrict__ Cl,
    int M, int N, int K,
    long long sA, long long sW, long long sBias, long long sC)
{
    __shared__ unsigned short sA_h[4096], sA_l[4096], sW_h[4096], sW_l[4096];
    const int t = threadIdx.x;
    const int z = blockIdx.z;
    Ah += (size_t)z * sA;  Al += (size_t)z * sA;
    Wh += (size_t)z * sW;  Wl += (size_t)z * sW;
    if (SPLIT) { Ch += (size_t)z * sC; Cl += (size_t)z * sC; }
    else       { C  += (size_t)z * sC; }
    const float* bp = bias ? (bias + (size_t)z * sBias) : nullptr;
    const int bn = blockIdx.x * 128, bm = blockIdx.y * 128;
    const int lane = t & 63, w = t >> 6;
    const int wm = (w & 1) * 64, wn = (w >> 1) * 64;
    const int r0 = t >> 2, kq = (t & 3) * 8;
    const int r1 = 64 + r0;
    const uint4 zero4 = make_uint4(0u, 0u, 0u, 0u);

    const unsigned short* pA0 = Ah + (size_t)(bm + r0) * K + kq;
    const unsigned short* pA1 = Ah + (size_t)(bm + r1) * K + kq;
    const unsigned short* pa0 = Al + (size_t)(bm + r0) * K + kq;
    const unsigned short* pa1 = Al + (size_t)(bm + r1) * K + kq;
    const bool v0 = (bn + r0) < N, v1 = (bn + r1) < N;
    const unsigned short* pW0 = Wh + (size_t)(bn + r0) * K + kq;
    const unsigned short* pW1 = Wh + (size_t)(bn + r1) * K + kq;
    const unsigned short* pw0 = Wl + (size_t)(bn + r0) * K + kq;
    const unsigned short* pw1 = Wl + (size_t)(bn + r1) * K + kq;

    uint4 rA0 = *(const uint4*)pA0, rA1 = *(const uint4*)pA1;
    uint4 ra0 = *(const uint4*)pa0, ra1 = *(const uint4*)pa1;
    uint4 rW0 = v0 ? *(const uint4*)pW0 : zero4;
    uint4 rW1 = v1 ? *(const uint4*)pW1 : zero4;
    uint4 rw0 = v0 ? *(const uint4*)pw0 : zero4;
    uint4 rw1 = v1 ? *(const uint4*)pw1 : zero4;

    v4f acc[4][4] = {};
    const int i0 = (r0 * 32 + kq) ^ ((r0 & 7) << 3);
    const int i1 = (r1 * 32 + kq) ^ ((r1 & 7) << 3);
    const int KT = K >> 5;

    for (int kt = 0; kt < KT; ++kt) {
        __syncthreads();
        *(uint4*)&sA_h[i0] = rA0;  *(uint4*)&sA_h[i1] = rA1;
        *(uint4*)&sA_l[i0] = ra0;  *(uint4*)&sA_l[i1] = ra1;
        *(uint4*)&sW_h[i0] = rW0;  *(uint4*)&sW_h[i1] = rW1;
        *(uint4*)&sW_l[i0] = rw0;  *(uint4*)&sW_l[i1] = rw1;
        __syncthreads();
        if (kt + 1 < KT) {
            int o = (kt + 1) * 32;
            rA0 = *(const uint4*)(pA0 + o);  rA1 = *(const uint4*)(pA1 + o);
            ra0 = *(const uint4*)(pa0 + o);  ra1 = *(const uint4*)(pa1 + o);
            rW0 = v0 ? *(const uint4*)(pW0 + o) : zero4;
            rW1 = v1 ? *(const uint4*)(pW1 + o) : zero4;
            rw0 = v0 ? *(const uint4*)(pw0 + o) : zero4;
            rw1 = v1 ? *(const uint4*)(pw1 + o) : zero4;
        }
        const int fr = lane & 15, fq = (lane >> 4) * 8;
        v8s ahf[4], alf[4], bhf[4], blf[4];
        #pragma unroll
        for (int i = 0; i < 4; ++i) {
            int ar = wm + i * 16 + fr;
            int br = wn + i * 16 + fr;
            int ai = (ar * 32 + fq) ^ ((ar & 7) << 3);
            int bi = (br * 32 + fq) ^ ((br & 7) << 3);
            ahf[i] = *(const v8s*)&sA_h[ai];
            alf[i] = *(const v8s*)&sA_l[ai];
            bhf[i] = *(const v8s*)&sW_h[bi];
            blf[i] = *(const v8s*)&sW_l[bi];
        }
        #pragma unroll
        for (int mi = 0; mi < 4; ++mi)
            #pragma unroll
            for (int ni = 0; ni < 4; ++ni) {
                acc[mi][ni] = __builtin_amdgcn_mfma_f32_16x16x32_bf16(ahf[mi], bhf[ni], acc[mi][ni], 0, 0, 0);
                acc[mi][ni] = __builtin_amdgcn_mfma_f32_16x16x32_bf16(ahf[mi], blf[ni], acc[mi][ni], 0, 0, 0);
                acc[mi][ni] = __builtin_amdgcn_mfma_f32_16x16x32_bf16(alf[mi], bhf[ni], acc[mi][ni], 0, 0, 0);
            }
    }

    const int er = (lane >> 4) * 4, ec = lane & 15;  // C/D: col=lane&15, row=quad*4+reg
    #pragma unroll
    for (int mi = 0; mi < 4; ++mi)
        #pragma unroll
        for (int ni = 0; ni < 4; ++ni) {
            int m = bm + wm + mi * 16 + er;
            int n = bn + wn + ni * 16 + ec;
            if (n < N) {
                float bv = bp ? bp[n] : 0.0f;
                #pragma unroll
                for (int r = 0; r < 4; ++r) {
                    float val = acc[mi][ni][r] + bv;
                    if (ACT == 1) val = val / (1.0f + expf(-val));   // swish
                    if (SPLIT) {
                        unsigned short hv = bf_hi(val);
                        Ch[(size_t)(m + r) * N + n] = hv;
                        Cl[(size_t)(m + r) * N + n] = bf_hi(val - bf_tof(hv));
                    } else {
                        C[(size_t)(m + r) * N + n] = val;
                    }
                }
            }
        }
    (void)M;
}

// ---------------------------------------------------------------------------
// Compression GEMM via bf16 MFMA hi/lo split, split-K=8.  R1-verified body.
// 1D grid + bijective XCD swizzle (m204): each XCD owns one split-K chunk z;
// the 4 bn-sibling blocks of each bm run adjacent on the same XCD so each
// 3.28 MB A-panel is fetched into that XCD's L2 once.
// ---------------------------------------------------------------------------
__global__ __launch_bounds__(256) void k_g3mfma(
    const unsigned short* __restrict__ Ah, const unsigned short* __restrict__ Al,
    const unsigned short* __restrict__ Wh, const unsigned short* __restrict__ Wl,
    float* __restrict__ part)
{
    __shared__ unsigned short sAh[4096], sAl[4096], sWh[4096], sWl[4096];
    const int t  = threadIdx.x;
    // XCD swizzle: hw block h -> work wk = (h%8)*100 + h/8  (800 = 8*100, bijective)
    const int hwid = blockIdx.x;
    const int wk = (hwid & 7) * 100 + (hwid >> 3);
    const int bn = (wk & 3) * 128;         // N in [0,512)
    const int bm = ((wk >> 2) % 25) * 128; // M in [0,3200)
    const int z  = wk / 100;               // split-K chunk (== hwid%8)
    const int lane = t & 63, w = t >> 6;
    const int wm = (w & 1) * 64, wn = (w >> 1) * 64;
    const size_t K = KBIG;
    const int r0 = t >> 2, kq = (t & 3) * 8;
    const int r1 = 64 + r0;

    const unsigned short* pA0 = Ah + (size_t)(bm + r0) * K + z * 3200 + kq;
    const unsigned short* pA1 = Ah + (size_t)(bm + r1) * K + z * 3200 + kq;
    const unsigned short* pa0 = Al + (size_t)(bm + r0) * K + z * 3200 + kq;
    const unsigned short* pa1 = Al + (size_t)(bm + r1) * K + z * 3200 + kq;
    const unsigned short* pW0 = Wh + (size_t)(bn + r0) * K + z * 3200 + kq;
    const unsigned short* pW1 = Wh + (size_t)(bn + r1) * K + z * 3200 + kq;
    const unsigned short* pw0 = Wl + (size_t)(bn + r0) * K + z * 3200 + kq;
    const unsigned short* pw1 = Wl + (size_t)(bn + r1) * K + z * 3200 + kq;

    uint4 rA0 = *(const uint4*)pA0, rA1 = *(const uint4*)pA1;
    uint4 ra0 = *(const uint4*)pa0, ra1 = *(const uint4*)pa1;
    uint4 rW0 = *(const uint4*)pW0, rW1 = *(const uint4*)pW1;
    uint4 rw0 = *(const uint4*)pw0, rw1 = *(const uint4*)pw1;

    v4f acc[4][4] = {};
    const int i0 = (r0 * 32 + kq) ^ ((r0 & 7) << 3);
    const int i1 = (r1 * 32 + kq) ^ ((r1 & 7) << 3);

    for (int kt = 0; kt < 100; ++kt) {
        __syncthreads();
        *(uint4*)&sAh[i0] = rA0;  *(uint4*)&sAh[i1] = rA1;
        *(uint4*)&sAl[i0] = ra0;  *(uint4*)&sAl[i1] = ra1;
        *(uint4*)&sWh[i0] = rW0;  *(uint4*)&sWh[i1] = rW1;
        *(uint4*)&sWl[i0] = rw0;  *(uint4*)&sWl[i1] = rw1;
        __syncthreads();
        if (kt < 99) {
            int off = (kt + 1) * 32;
            rA0 = *(const uint4*)(pA0 + off);  rA1 = *(const uint4*)(pA1 + off);
            ra0 = *(const uint4*)(pa0 + off);  ra1 = *(const uint4*)(pa1 + off);
            rW0 = *(const uint4*)(pW0 + off);  rW1 = *(const uint4*)(pW1 + off);
            rw0 = *(const uint4*)(pw0 + off);  rw1 = *(const uint4*)(pw1 + off);
        }
        const int fr = lane & 15, fq = (lane >> 4) * 8;
        v8s ah[4], al[4], bh[4], bl[4];
        #pragma unroll
        for (int i = 0; i < 4; ++i) {
            int ar = wm + i * 16 + fr;
            int br = wn + i * 16 + fr;
            int ai = (ar * 32 + fq) ^ ((ar & 7) << 3);
            int bi = (br * 32 + fq) ^ ((br & 7) << 3);
            ah[i] = *(const v8s*)&sAh[ai];
            al[i] = *(const v8s*)&sAl[ai];
            bh[i] = *(const v8s*)&sWh[bi];
            bl[i] = *(const v8s*)&sWl[bi];
        }
        #pragma unroll
        for (int mi = 0; mi < 4; ++mi)
            #pragma unroll
            for (int ni = 0; ni < 4; ++ni) {
                acc[mi][ni] = __builtin_amdgcn_mfma_f32_16x16x32_bf16(ah[mi], bh[ni], acc[mi][ni], 0, 0, 0);
                acc[mi][ni] = __builtin_amdgcn_mfma_f32_16x16x32_bf16(ah[mi], bl[ni], acc[mi][ni], 0, 0, 0);
                acc[mi][ni] = __builtin_amdgcn_mfma_f32_16x16x32_bf16(al[mi], bh[ni], acc[mi][ni], 0, 0, 0);
            }
    }

    const int er = (lane >> 4) * 4, ec = lane & 15;
    float* cp = part + (size_t)z * NBA * 512;
    #pragma unroll
    for (int mi = 0; mi < 4; ++mi)
        #pragma unroll
        for (int ni = 0; ni < 4; ++ni) {
            int m = bm + wm + mi * 16 + er;
            int n = bn + wn + ni * 16 + ec;
            #pragma unroll
            for (int r = 0; r < 4; ++r)
                cp[(size_t)(m + r) * 512 + n] = acc[mi][ni][r];
        }
}

// ---------------------------------------------------------------------------
// Split-K reduce + fold-bias + swish, emitting bf16 hi/lo directly.
// ---------------------------------------------------------------------------
__global__ __launch_bounds__(256) void k_g3red(
    const float* __restrict__ part, const float* __restrict__ comp_b1,
    const float* __restrict__ E0, const float* __restrict__ Corr,
    const int* __restrict__ nvalid,
    unsigned short* __restrict__ oh, unsigned short* __restrict__ ol)
{
    const int i4 = (blockIdx.x * 256 + threadIdx.x) * 4;
    const int ba = i4 >> 9, n = i4 & 511;
    const size_t S = (size_t)NBA * 512;
    float4 s = *(const float4*)(part + i4);
    #pragma unroll
    for (int zz = 1; zz < 8; ++zz) {
        float4 p = *(const float4*)(part + zz * S + i4);
        s.x += p.x; s.y += p.y; s.z += p.z; s.w += p.w;
    }
    int nv = nvalid[ba];
    float4 b  = *(const float4*)(comp_b1 + n);
    float4 e  = *(const float4*)(E0 + n);
    float4 c  = *(const float4*)(Corr + nv * 512 + n);
    float r0 = s.x + b.x + e.x + c.x;
    float r1 = s.y + b.y + e.y + c.y;
    float r2 = s.z + b.z + e.z + c.z;
    float r3 = s.w + b.w + e.w + c.w;
    float4 o;
    o.x = r0 / (1.0f + expf(-r0));
    o.y = r1 / (1.0f + expf(-r1));
    o.z = r2 / (1.0f + expf(-r2));
    o.w = r3 / (1.0f + expf(-r3));
    ushort4 h, l;
    h.x = bf_hi(o.x); l.x = bf_hi(o.x - bf_tof(h.x));
    h.y = bf_hi(o.y); l.y = bf_hi(o.y - bf_tof(h.y));
    h.z = bf_hi(o.z); l.z = bf_hi(o.z - bf_tof(h.z));
    h.w = bf_hi(o.w); l.w = bf_hi(o.w - bf_tof(h.w));
    *(ushort4*)(oh + i4) = h;
    *(ushort4*)(ol + i4) = l;
}

// ---------------------------------------------------------------------------
// Fused attention; emits swish(Hm) directly as bf16 hi/lo (feeds fp1 GEMM).
// ---------------------------------------------------------------------------
__global__ __launch_bounds__(256) void k_attn(
    const float* __restrict__ Qb, const float* __restrict__ Kb,
    const float* __restrict__ Vb, const float* __restrict__ conn,
    unsigned short* __restrict__ Oh, unsigned short* __restrict__ Ol)
{
    __shared__ float sKV[256][101];
    __shared__ float sAl[50][100];
    __shared__ float sQ[2][256];
    __shared__ float sRed[2][2];

    const int t = threadIdx.x;
    const int half = blockIdx.x, b = blockIdx.y, n = blockIdx.z;
    const size_t base = ((size_t)n * NBA + b * 100) * 256;

    const float* Kp = Kb + base;
    for (int r = 0; r < 100; ++r) sKV[t][r] = Kp[(size_t)r * 256 + t];
    __syncthreads();

    const float* Qp = Qb + base;
    const int pair = t >> 7, tt = t & 127, lane = t & 63, wvi = t >> 6;

    for (int rr = 0; rr < 25; ++rr) {
        const int row0 = half * 50 + rr * 2;
        const int lr = rr * 2 + pair;
        __syncthreads();
        sQ[0][t] = Qp[(size_t)(row0)*256 + t];
        sQ[1][t] = Qp[(size_t)(row0 + 1) * 256 + t];
        __syncthreads();
        float sc = 0.0f;
        if (tt < 100) {
            const float* qr = sQ[pair];
            float p0 = 0.f, p1 = 0.f, p2 = 0.f, p3 = 0.f;
            #pragma unroll 4
            for (int c = 0; c < 256; c += 4) {
                p0 += qr[c]     * sKV[c][tt];
                p1 += qr[c + 1] * sKV[c + 1][tt];
                p2 += qr[c + 2] * sKV[c + 2][tt];
                p3 += qr[c + 3] * sKV[c + 3][tt];
            }
            sc = ((p0 + p1) + (p2 + p3)) * 0.0625f + conn[(row0 + pair) * 100 + tt];
            sAl[lr][tt] = sc;
        }
        __syncthreads();
        if ((wvi & 1) == 0) {
            int p = wvi >> 1;
            int r2 = rr * 2 + p;
            float m = sAl[r2][lane];
            if (lane < 36) m = fmaxf(m, sAl[r2][lane + 64]);
            #pragma unroll
            for (int off = 32; off > 0; off >>= 1)
                m = fmaxf(m, __shfl_down(m, off));
            if (lane == 0) sRed[0][p] = m;
        }
        __syncthreads();
        float ex = 0.0f;
        if (tt < 100) {
            ex = expf(sc - sRed[0][pair]);
            sAl[lr][tt] = ex;
        }
        __syncthreads();
        if ((wvi & 1) == 0) {
            int p = wvi >> 1;
            int r2 = rr * 2 + p;
            float s = sAl[r2][lane];
            if (lane < 36) s += sAl[r2][lane + 64];
            #pragma unroll
            for (int off = 32; off > 0; off >>= 1)
                s += __shfl_down(s, off);
            if (lane == 0) sRed[1][p] = s;
        }
        __syncthreads();
        if (tt < 100) sAl[lr][tt] = ex / sRed[1][pair];
    }
    __syncthreads();

    const float* Vp = Vb + base;
    for (int r = 0; r < 100; ++r) sKV[t][r] = Vp[(size_t)r * 256 + t];
    __syncthreads();

    for (int rr = 0; rr < 50; ++rr) {
        int row = half * 50 + rr;
        float a = 0.0f;
        #pragma unroll 4
        for (int j = 0; j < 100; ++j) a += sAl[rr][j] * sKV[t][j];
        float sw = a / (1.0f + expf(-a));   // swish fused (fp1 consumes swish(Hm))
        size_t oidx = base + (size_t)row * 256 + t;
        unsigned short hv = bf_hi(sw);
        Oh[oidx] = hv;
        Ol[oidx] = bf_hi(sw - bf_tof(hv));
    }
}

// ---------------------------------------------------------------------------
// Per-head layernorm over HID + mean over heads -> new h (bf16 hi/lo).
// ---------------------------------------------------------------------------
__global__ __launch_bounds__(256) void k_ln_mean(
    const float* __restrict__ t2b, const float* __restrict__ ln_g,
    const float* __restrict__ ln_b,
    unsigned short* __restrict__ hh, unsigned short* __restrict__ hl)
{
    __shared__ float so[4][256];
    const int ba = blockIdx.x, t = threadIdx.x;
    const int n = t >> 6, lane = t & 63;
    const float* tr = t2b + ((size_t)n * NBA + ba) * HID;
    float4 v = *(const float4*)(tr + lane * 4);
    float s1 = v.x + v.y + v.z + v.w;
    float s2 = v.x * v.x + v.y * v.y + v.z * v.z + v.w * v.w;
    #pragma unroll
    for (int off = 32; off > 0; off >>= 1) {
        s1 += __shfl_down(s1, off);
        s2 += __shfl_down(s2, off);
    }
    s1 = __shfl(s1, 0);
    s2 = __shfl(s2, 0);
    float m = s1 * (1.0f / 256.0f);
    float var = s2 * (1.0f / 256.0f) - m * m;
    float rstd = 1.0f / sqrtf(var + 1e-5f);
    float4 gv = *(const float4*)(ln_g + n * HID + lane * 4);
    float4 bv = *(const float4*)(ln_b + n * HID + lane * 4);
    float4 o;
    o.x = (v.x - m) * rstd * gv.x + bv.x;
    o.y = (v.y - m) * rstd * gv.y + bv.y;
    o.z = (v.z - m) * rstd * gv.z + bv.z;
    o.w = (v.w - m) * rstd * gv.w + bv.w;
    *(float4*)&so[n][lane * 4] = o;
    __syncthreads();
    float hv = 0.25f * (so[0][t] + so[1][t] + so[2][t] + so[3][t]);
    unsigned short hi = bf_hi(hv);
    size_t oidx = (size_t)ba * HID + t;
    hh[oidx] = hi;
    hl[oidx] = bf_hi(hv - bf_tof(hi));
}

// ---------------------------------------------------------------------------
extern "C" void kernel_launch(void* const* d_in, const int* in_sizes, int n_in,
                              void* d_out, int out_size, void* d_ws, size_t ws_size,
                              hipStream_t stream)
{
    const float* x       = (const float*)d_in[0];
    const float* fourB   = (const float*)d_in[1];
    const float* enc_W1  = (const float*)d_in[2];
    const float* enc_b1  = (const float*)d_in[3];
    const float* enc_W2  = (const float*)d_in[4];
    const float* enc_b2  = (const float*)d_in[5];
    const float* pad_tok = (const float*)d_in[6];
    const float* comp_W1 = (const float*)d_in[7];
    const float* comp_b1 = (const float*)d_in[8];
    const float* comp_W2 = (const float*)d_in[9];
    const float* comp_b2 = (const float*)d_in[10];
    const float* conn    = (const float*)d_in[11];
    const float* qW      = (const float*)d_in[12];
    const float* kW      = (const float*)d_in[13];
    const float* vW      = (const float*)d_in[14];
    const float* fpW1    = (const float*)d_in[15];
    const float* fpb1    = (const float*)d_in[16];
    const float* fpW2    = (const float*)d_in[17];
    const float* fpb2    = (const float*)d_in[18];
    const float* ln_g    = (const float*)d_in[19];
    const float* ln_b    = (const float*)d_in[20];
    const float* out_W   = (const float*)d_in[21];
    const float* out_b   = (const float*)d_in[22];
    float* outp = (float*)d_out;

    // Workspace budget: V1 (passed) = 507,761,152 B; V2/V3 (crashed) =
    // 517,591,552 B -> ws limit lies in between. This build: 504,484,352 B.
    char* ws = (char*)d_ws;
    size_t off = 0;
    auto alloc = [&](size_t bytes) -> void* {
        void* p = (void*)(ws + off);
        off += (bytes + 255) & ~(size_t)255;
        return p;
    };
    int*   idxb = (int*)  alloc((size_t)NBA * EMAX * 4);
    float* valb = (float*)alloc((size_t)NBA * EMAX * 4);
    int*   nval = (int*)  alloc((size_t)NBA * 4);
    unsigned short* g1h = (unsigned short*)alloc((size_t)NBA * KBIG * 2);  // 163.8 MB
    unsigned short* g1l = (unsigned short*)alloc((size_t)NBA * KBIG * 2);  // 163.8 MB
    float* W2T  = (float*)alloc((size_t)256 * 256 * 4);
    float* W1p  = (float*)alloc((size_t)512 * KBIG * 4);     // 52.4 MB; reused as split-K partials
    float* part = W1p;                                       // alias (W1p dead after k_wsplit)
    unsigned short* Whi = (unsigned short*)alloc((size_t)512 * KBIG * 2);
    unsigned short* Wlo = (unsigned short*)alloc((size_t)512 * KBIG * 2);
    float* Dt   = (float*)alloc((size_t)100 * 512 * 4);
    float* Corr = (float*)alloc((size_t)101 * 512 * 4);
    float* E0   = (float*)alloc((size_t)512 * 4);
    // --- contiguous region: Qb | Kb | Vb | asplh | aspll ---
    // aliased earlier as cW1h/cW1l (bf16 split of comp_W1, dead after fold)
    float* Qb   = (float*)alloc((size_t)NHEAD * NBA * HID * 4);   // 13,107,200 B
    float* Kb   = (float*)alloc((size_t)NHEAD * NBA * HID * 4);
    float* Vb   = (float*)alloc((size_t)NHEAD * NBA * HID * 4);
    unsigned short* asplh = (unsigned short*)alloc((size_t)NHEAD * NBA * HID * 2); // 6.55 MB
    unsigned short* aspll = (unsigned short*)alloc((size_t)NHEAD * NBA * HID * 2);
    unsigned short* cW1h = (unsigned short*)Qb;   // spans Qb+Kb   (26.2 MB)
    unsigned short* cW1l = (unsigned short*)Vb;   // spans Vb+asplh+aspll (26.2 MB)
    // bspl: ALIAS into g1h (163.8 MB, dead after k_g3mfma; bspl first written
    // by the comp_W2 GEMM which is strictly later in the stream). Saves 13.1 MB
    // of fresh workspace vs R2/R3 (the overflow that caused both crashes).
    unsigned short* bsplh = g1h;
    unsigned short* bspll = g1h + (size_t)NHEAD * NBA * HID;
    // weight splits (persistent through the call)
    unsigned short* w2tH = (unsigned short*)alloc((size_t)256 * 256 * 2);
    unsigned short* w2tL = (unsigned short*)alloc((size_t)256 * 256 * 2);
    unsigned short* qkvWh = (unsigned short*)alloc((size_t)3 * NHEAD * HID * HID * 2);
    unsigned short* qkvWl = (unsigned short*)alloc((size_t)3 * NHEAD * HID * HID * 2);
    unsigned short* f1Wh = (unsigned short*)alloc((size_t)NHEAD * HID * HID * 2);
    unsigned short* f1Wl = (unsigned short*)alloc((size_t)NHEAD * HID * HID * 2);
    unsigned short* f2Wh = (unsigned short*)alloc((size_t)NHEAD * HID * HID * 2);
    unsigned short* f2Wl = (unsigned short*)alloc((size_t)NHEAD * HID * HID * 2);
    unsigned short* c2Wh = (unsigned short*)alloc((size_t)HID * 512 * 2);
    unsigned short* c2Wl = (unsigned short*)alloc((size_t)HID * 512 * 2);
    unsigned short* oWh  = (unsigned short*)alloc((size_t)NOUT * HID * 2);
    unsigned short* oWl  = (unsigned short*)alloc((size_t)NOUT * HID * 2);
    // aliases (lifetimes disjoint within a step)
    float* t2b  = Vb;   // V dead after attn

    const long long sW = (long long)HID * HID;   // 65536
    const long long sC = (long long)NBA * HID;   // 819200

    k_extract<<<NBA, 64, 0, stream>>>(x, idxb, valb, nval);
    k_g1<<<NBA * EMAX / 16, 256, 0, stream>>>(idxb, valb, nval, fourB,
                                              enc_W1, enc_b1, g1h, g1l);

    // fold enc_W2 into comp_W1 (split-bf16 MFMA)
    k_w2t<<<256, 256, 0, stream>>>(enc_W2, W2T);
    k_wsplit<<<256 * 256 / 1024, 256, 0, stream>>>(W2T, w2tH, w2tL);
    k_wsplit<<<512 * KBIG / 1024, 256, 0, stream>>>(comp_W1, cW1h, cW1l);
    k_gemmbf<0, 0><<<dim3(2, 400, 1), 256, 0, stream>>>(
        cW1h, cW1l, w2tH, w2tL, nullptr, W1p, nullptr, nullptr,
        512 * EMAX, 256, 256, 0, 0, 0, 0);
    k_wsplit<<<512 * KBIG / 1024, 256, 0, stream>>>(W1p, Whi, Wlo);
    k_tables<<<512, 256, 0, stream>>>(comp_W1, pad_tok, enc_b2, Dt, E0);
    k_suffix<<<2, 256, 0, stream>>>(Dt, Corr);

    // one-time weight splits
    k_wsplit<<<NHEAD * 65536 / 1024, 256, 0, stream>>>(qW, qkvWh, qkvWl);
    k_wsplit<<<NHEAD * 65536 / 1024, 256, 0, stream>>>(kW, qkvWh + NHEAD * 65536, qkvWl + NHEAD * 65536);
    k_wsplit<<<NHEAD * 65536 / 1024, 256, 0, stream>>>(vW, qkvWh + 2 * NHEAD * 65536, qkvWl + 2 * NHEAD * 65536);
    k_wsplit<<<NHEAD * 65536 / 1024, 256, 0, stream>>>(fpW1, f1Wh, f1Wl);
    k_wsplit<<<NHEAD * 65536 / 1024, 256, 0, stream>>>(fpW2, f2Wh, f2Wl);
    k_wsplit<<<HID * 512 / 1024, 256, 0, stream>>>(comp_W2, c2Wh, c2Wl);
    k_wsplit<<<NOUT * HID / 1024, 256, 0, stream>>>(out_W, oWh, oWl);

    // compression GEMM (M=3200,N=512,K=25600), split-K=8, XCD-swizzled 1D grid
    k_g3mfma<<<800, 256, 0, stream>>>(g1h, g1l, Whi, Wlo, part);
    // reduce + bias-fold + swish -> h1s split into aspl
    k_g3red<<<NBA * 512 / 1024, 256, 0, stream>>>(part, comp_b1, E0, Corr, nval, asplh, aspll);
    // h = h1s @ comp_W2^T + b2 -> split directly into bspl (g1h region, now dead)
    k_gemmbf<0, 1><<<dim3(2, 25, 1), 256, 0, stream>>>(
        asplh, aspll, c2Wh, c2Wl, comp_b2, nullptr, bsplh, bspll,
        NBA, HID, 512, 0, 0, 0, 0);

    for (int step = 0; step < 3; ++step) {
        // QKV: 12-batched, reads h-split (bspl), writes fp32 Q/K/V
        k_gemmbf<0, 0><<<dim3(2, 25, 12), 256, 0, stream>>>(
            bsplh, bspll, qkvWh, qkvWl, nullptr, Qb, nullptr, nullptr,
            NBA, HID, HID, 0, sW, 0, sC);
        // attn emits swish(Hm) split into aspl
        k_attn<<<dim3(2, NBATCH, NHEAD), 256, 0, stream>>>(Qb, Kb, Vb, conn, asplh, aspll);
        // fp1: swish epilogue + split out into bspl
        k_gemmbf<1, 1><<<dim3(2, 25, 4), 256, 0, stream>>>(
            asplh, aspll, f1Wh, f1Wl, fpb1, nullptr, bsplh, bspll,
            NBA, HID, HID, sC, sW, HID, sC);
        // fp2: fp32 out into t2b (=Vb, dead after attn)
        k_gemmbf<0, 0><<<dim3(2, 25, 4), 256, 0, stream>>>(
            bsplh, bspll, f2Wh, f2Wl, fpb2, t2b, nullptr, nullptr,
            NBA, HID, HID, sC, sW, HID, sC);
        // layernorm + head-mean -> next h split into bspl
        k_ln_mean<<<NBA, 256, 0, stream>>>(t2b, ln_g, ln_b, bsplh, bspll);
    }

    // out = h @ out_W^T + out_b  (M=3200, N=10000, K=256)
    k_gemmbf<0, 0><<<dim3(79, 25, 1), 256, 0, stream>>>(
        bsplh, bspll, oWh, oWl, out_b, outp, nullptr, nullptr,
        NBA, NOUT, HID, 0, 0, 0, 0);

    (void)in_sizes; (void)n_in; (void)out_size; (void)ws_size;
}

// Round 5
// 1825.029 us; speedup vs baseline: 1.4064x; 1.0438x over previous
//
#include <hip/hip_runtime.h>
#include <cstdint>
#include <cstddef>

#define NBATCH 32
#define NAGENT 100
#define NDIM   10000
#define HID    256
#define NHEAD  4
#define NOUT   10000
#define NFREQ  16
#define EMAX   100
#define NBA    3200                        // NBATCH * NAGENT
#define KBIG   25600                       // EMAX * HID
#define TWO_PI 6.283185307179586476925f

typedef float  v4f  __attribute__((ext_vector_type(4)));
typedef short  v8s  __attribute__((ext_vector_type(8)));

__device__ __forceinline__ unsigned short bf_hi(float f) {
    unsigned int u = __float_as_uint(f);
    return (unsigned short)((u + 0x7FFFu + ((u >> 16) & 1u)) >> 16);
}
__device__ __forceinline__ float bf_tof(unsigned short h) {
    return __uint_as_float(((unsigned int)h) << 16);
}

// async global->LDS, 16B per lane; LDS dest = wave-uniform base + lane*16
__device__ __forceinline__ void gld16(const void* g, void* l) {
    __builtin_amdgcn_global_load_lds(
        (const __attribute__((address_space(1))) void*)g,
        (__attribute__((address_space(3))) void*)l, 16, 0, 0);
}

// ---------------------------------------------------------------------------
// Stage 1: per-(b,a) stream compaction of nonzeros (ascending flat index),
// truncated to EMAX. One wave per (b,a). Matches stable argsort order.
// ---------------------------------------------------------------------------
__global__ __launch_bounds__(64) void k_extract(const float* __restrict__ x,
                                                int* __restrict__ idxb,
                                                float* __restrict__ valb,
                                                int* __restrict__ nvalid)
{
    const int ba = blockIdx.x;
    const float* xr = x + (size_t)ba * NDIM;
    const int lane = threadIdx.x;
    int base = 0;
    for (int c0 = 0; c0 < NDIM; c0 += 64) {
        int i = c0 + lane;
        float v = (i < NDIM) ? xr[i] : 0.0f;
        unsigned long long m = __ballot(v != 0.0f);
        if (v != 0.0f) {
            int p = base + __popcll(m & ((1ull << lane) - 1ull));
            if (p < EMAX) {
                idxb[(size_t)ba * EMAX + p] = i;
                valb[(size_t)ba * EMAX + p] = v;
            }
        }
        base += __popcll(m);
        if (base >= EMAX) break;           // uniform across wave
    }
    if (lane == 0) nvalid[ba] = base < EMAX ? base : EMAX;
}

// ---------------------------------------------------------------------------
// Stage 2: fourier + encoder layer-1 only. g1 = swish(feat @ enc_W1^T + b1),
// zeroed for invalid slots; written as bf16 hi/lo pair (exact to ~2^-17).
// ---------------------------------------------------------------------------
__global__ __launch_bounds__(256) void k_g1(
    const int* __restrict__ idxb, const float* __restrict__ valb,
    const int* __restrict__ nvalid, const float* __restrict__ fourB,
    const float* __restrict__ W1, const float* __restrict__ b1,
    unsigned short* __restrict__ g1h, unsigned short* __restrict__ g1l)
{
    __shared__ float s_feat[16][36];
    __shared__ float s_w[8448];            // enc_W1 256x33
    __shared__ float s_b1v[256];
    __shared__ int   s_idx[16];
    __shared__ int   s_valid[16];

    const int t  = threadIdx.x;
    const int g0 = blockIdx.x * 16;

    if (t < 16) {
        int g = g0 + t;
        int ba = g / 100, slot = g - ba * 100;
        int valid = (slot < nvalid[ba]) ? 1 : 0;
        s_valid[t]   = valid;
        s_idx[t]     = valid ? idxb[g] : 0;
        s_feat[t][0] = valid ? valb[g] : 0.0f;
    }
    s_b1v[t] = b1[t];
    for (int i = t; i < 8448; i += 256) s_w[i] = W1[i];
    __syncthreads();

    {   // Fourier features: 16 entries x 16 freqs = 256 work items
        int ent = t >> 4, f = t & 15;
        float sv = 0.0f, cv = 0.0f;
        if (s_valid[ent]) {
            int id = s_idx[ent];
            float row = (float)(id / 100);
            float col = (float)(id % 100);
            float pr = TWO_PI * (row * fourB[2 * f] + col * fourB[2 * f + 1]);
            sv = sinf(pr); cv = cosf(pr);
        }
        s_feat[ent][1 + f]  = sv;
        s_feat[ent][17 + f] = cv;
    }
    __syncthreads();

    const float* wr = &s_w[t * 33];        // stride 33: conflict-free (33%32==1)
    for (int ent = 0; ent < 16; ++ent) {
        float a = s_b1v[t];
        #pragma unroll
        for (int c = 0; c < 33; ++c) a += s_feat[ent][c] * wr[c];
        float g = a / (1.0f + expf(-a));   // swish
        g = s_valid[ent] ? g : 0.0f;
        unsigned short h = bf_hi(g);
        unsigned short l = bf_hi(g - bf_tof(h));
        size_t o = (size_t)(g0 + ent) * 256 + t;
        g1h[o] = h;
        g1l[o] = l;
    }
}

// ---------------------------------------------------------------------------
// W2T[k'][k] = W2[k][k']  (tiny, 256 KB)
// ---------------------------------------------------------------------------
__global__ void k_w2t(const float* __restrict__ W2, float* __restrict__ W2T)
{
    int kp = blockIdx.x, k = threadIdx.x;
    W2T[kp * 256 + k] = W2[k * 256 + kp];
}

// ---------------------------------------------------------------------------
// fp32 -> bf16 hi/lo elementwise split (generic; total elems = grid*1024)
// ---------------------------------------------------------------------------
__global__ __launch_bounds__(256) void k_wsplit(const float* __restrict__ src,
                                                unsigned short* __restrict__ hi,
                                                unsigned short* __restrict__ lo)
{
    int i = (blockIdx.x * 256 + threadIdx.x) * 4;
    float4 f = *(const float4*)(src + i);
    ushort4 h, l;
    h.x = bf_hi(f.x); l.x = bf_hi(f.x - bf_tof(h.x));
    h.y = bf_hi(f.y); l.y = bf_hi(f.y - bf_tof(h.y));
    h.z = bf_hi(f.z); l.z = bf_hi(f.z - bf_tof(h.z));
    h.w = bf_hi(f.w); l.w = bf_hi(f.w - bf_tof(h.w));
    *(ushort4*)(hi + i) = h;
    *(ushort4*)(lo + i) = l;
}

// ---------------------------------------------------------------------------
// Bias tables for the W2-fold.
// ---------------------------------------------------------------------------
__global__ __launch_bounds__(256) void k_tables(
    const float* __restrict__ W1, const float* __restrict__ pad,
    const float* __restrict__ b2, float* __restrict__ D, float* __restrict__ E0)
{
    __shared__ float red[4];
    const int n = blockIdx.x;
    const int t = threadIdx.x, lane = t & 63, w = t >> 6;
    const float pm = pad[t] - b2[t];
    const float bb = b2[t];
    const float* wr = W1 + (size_t)n * KBIG;
    float eb = 0.0f;
    for (int s = 0; s < 100; ++s) {
        float wv = wr[s * 256 + t];
        float p = pm * wv;
        eb += bb * wv;
        #pragma unroll
        for (int o = 32; o > 0; o >>= 1) p += __shfl_down(p, o);
        if (lane == 0) red[w] = p;
        __syncthreads();
        if (t == 0) D[s * 512 + n] = red[0] + red[1] + red[2] + red[3];
        __syncthreads();
    }
    #pragma unroll
    for (int o = 32; o > 0; o >>= 1) eb += __shfl_down(eb, o);
    if (lane == 0) red[w] = eb;
    __syncthreads();
    if (t == 0) E0[n] = red[0] + red[1] + red[2] + red[3];
}

__global__ void k_suffix(const float* __restrict__ D, float* __restrict__ Corr)
{
    int n = blockIdx.x * 256 + threadIdx.x;   // 512 columns
    float c = 0.0f;
    Corr[100 * 512 + n] = 0.0f;
    for (int s = 99; s >= 0; --s) { c += D[s * 512 + n]; Corr[s * 512 + n] = c; }
}

// ---------------------------------------------------------------------------
// Generic split-bf16 MFMA GEMM: C = act(A @ W^T + bias), fp32-grade accuracy
// via hi/lo compensation (3 MFMAs: hh, hl, lh). 128x128 tile, BK=32, 4 waves
// each 64x64 (4x4 of 16x16x32 MFMA).
// NEW (m97 structure): global_load_lds width-16 staging into double-buffered
// LDS, ONE __syncthreads per K-step (compiler drains vmcnt+lgkmcnt there).
// W rows are CLAMPED to N-1 for OOB tiles (gld16 can't zero-fill); clamped
// columns are never written (n<N epilogue guard).
// SPLIT=1: emit bf16 hi/lo (Ch/Cl) instead of fp32 C.
// ---------------------------------------------------------------------------
template<int ACT, int SPLIT>
__global__ __launch_bounds__(256) void k_gemmbf(
    const unsigned short* __restrict__ Ah, const unsigned short* __restrict__ Al,
    const unsigned short* __restrict__ Wh, const unsigned short* __restrict__ Wl,
    const float* __restrict__ bias, float* __restrict__ C,
    unsigned short* __restrict__ Ch, unsigned short* __restrict__ Cl,
    int M, int N, int K,
    long long sA, long long sW, long long sBias, long long sC)
{
    __shared__ unsigned short lds[2][4][4096];   // [buf][Ah,Al,Wh,Wl][128 rows x 32]
    const int t = threadIdx.x;
    const int z = blockIdx.z;
    Ah += (size_t)z * sA;  Al += (size_t)z * sA;
    Wh += (size_t)z * sW;  Wl += (size_t)z * sW;
    if (SPLIT) { Ch += (size_t)z * sC; Cl += (size_t)z * sC; }
    else       { C  += (size_t)z * sC; }
    const float* bp = bias ? (bias + (size_t)z * sBias) : nullptr;
    const int bn = blockIdx.x * 128, bm = blockIdx.y * 128;
    const int lane = t & 63, w = t >> 6;
    const int wm = (w & 1) * 64, wn = (w >> 1) * 64;

    // staging geometry: wave w covers rows [h*64 + w*16, +16) of each array;
    // lane l -> row +(l>>2), 16B octet (l&3). DMA dest = base + lane*16B.
    const int sr = w * 16 + (lane >> 2);
    const int so = (lane & 3) * 8;
    int rw0 = bn + sr;       if (rw0 >= N) rw0 = N - 1;   // clamp OOB W rows
    int rw1 = bn + 64 + sr;  if (rw1 >= N) rw1 = N - 1;
    const unsigned short* gA0 = Ah + (size_t)(bm + sr) * K + so;
    const unsigned short* gA1 = Ah + (size_t)(bm + 64 + sr) * K + so;
    const unsigned short* ga0 = Al + (size_t)(bm + sr) * K + so;
    const unsigned short* ga1 = Al + (size_t)(bm + 64 + sr) * K + so;
    const unsigned short* gW0 = Wh + (size_t)rw0 * K + so;
    const unsigned short* gW1 = Wh + (size_t)rw1 * K + so;
    const unsigned short* gw0 = Wl + (size_t)rw0 * K + so;
    const unsigned short* gw1 = Wl + (size_t)rw1 * K + so;
    const int lb0 = w * 512;          // ushort offset of wave chunk, half 0
    const int lb1 = 2048 + w * 512;   // half 1

    v4f acc[4][4] = {};
    const int fr = lane & 15, fq = (lane >> 4) * 8;
    const int KT = K >> 5;

#define STAGE_G(buf, o)                                                        \
    gld16(gA0 + (o), &lds[buf][0][lb0]); gld16(gA1 + (o), &lds[buf][0][lb1]);  \
    gld16(ga0 + (o), &lds[buf][1][lb0]); gld16(ga1 + (o), &lds[buf][1][lb1]);  \
    gld16(gW0 + (o), &lds[buf][2][lb0]); gld16(gW1 + (o), &lds[buf][2][lb1]);  \
    gld16(gw0 + (o), &lds[buf][3][lb0]); gld16(gw1 + (o), &lds[buf][3][lb1]);

    STAGE_G(0, 0);
    __syncthreads();                   // drains vmcnt: buf0 ready
    int cur = 0;
    for (int kt = 0; kt < KT; ++kt) {
        if (kt + 1 < KT) { STAGE_G(cur ^ 1, (kt + 1) * 32); }
        v8s ahf[4], alf[4], bhf[4], blf[4];
        #pragma unroll
        for (int i = 0; i < 4; ++i) {
            ahf[i] = *(const v8s*)&lds[cur][0][(wm + i * 16 + fr) * 32 + fq];
            alf[i] = *(const v8s*)&lds[cur][1][(wm + i * 16 + fr) * 32 + fq];
            bhf[i] = *(const v8s*)&lds[cur][2][(wn + i * 16 + fr) * 32 + fq];
            blf[i] = *(const v8s*)&lds[cur][3][(wn + i * 16 + fr) * 32 + fq];
        }
        #pragma unroll
        for (int mi = 0; mi < 4; ++mi)
            #pragma unroll
            for (int ni = 0; ni < 4; ++ni) {
                acc[mi][ni] = __builtin_amdgcn_mfma_f32_16x16x32_bf16(ahf[mi], bhf[ni], acc[mi][ni], 0, 0, 0);
                acc[mi][ni] = __builtin_amdgcn_mfma_f32_16x16x32_bf16(ahf[mi], blf[ni], acc[mi][ni], 0, 0, 0);
                acc[mi][ni] = __builtin_amdgcn_mfma_f32_16x16x32_bf16(alf[mi], bhf[ni], acc[mi][ni], 0, 0, 0);
            }
        __syncthreads();               // drains next-tile DMA + all LDS reads
        cur ^= 1;
    }
#undef STAGE_G

    const int er = (lane >> 4) * 4, ec = lane & 15;  // C/D: col=lane&15, row=quad*4+reg
    #pragma unroll
    for (int mi = 0; mi < 4; ++mi)
        #pragma unroll
        for (int ni = 0; ni < 4; ++ni) {
            int m = bm + wm + mi * 16 + er;
            int n = bn + wn + ni * 16 + ec;
            if (n < N) {
                float bv = bp ? bp[n] : 0.0f;
                #pragma unroll
                for (int r = 0; r < 4; ++r) {
                    float val = acc[mi][ni][r] + bv;
                    if (ACT == 1) val = val / (1.0f + expf(-val));   // swish
                    if (SPLIT) {
                        unsigned short hv = bf_hi(val);
                        Ch[(size_t)(m + r) * N + n] = hv;
                        Cl[(size_t)(m + r) * N + n] = bf_hi(val - bf_tof(hv));
                    } else {
                        C[(size_t)(m + r) * N + n] = val;
                    }
                }
            }
        }
    (void)M;
}

// ---------------------------------------------------------------------------
// Compression GEMM via bf16 MFMA hi/lo split, split-K=8.
// XCD-swizzled 1D grid (R4: FETCH 900->244 MB) + m97 gld_lds dbuf staging
// with ONE __syncthreads per K-step.
// ---------------------------------------------------------------------------
__global__ __launch_bounds__(256) void k_g3mfma(
    const unsigned short* __restrict__ Ah, const unsigned short* __restrict__ Al,
    const unsigned short* __restrict__ Wh, const unsigned short* __restrict__ Wl,
    float* __restrict__ part)
{
    __shared__ unsigned short lds[2][4][4096];
    const int t  = threadIdx.x;
    // XCD swizzle: hw block h -> work wk = (h%8)*100 + h/8  (800 = 8*100, bijective)
    const int hwid = blockIdx.x;
    const int wk = (hwid & 7) * 100 + (hwid >> 3);
    const int bn = (wk & 3) * 128;         // N in [0,512)
    const int bm = ((wk >> 2) % 25) * 128; // M in [0,3200)
    const int z  = wk / 100;               // split-K chunk (== hwid%8)
    const int lane = t & 63, w = t >> 6;
    const int wm = (w & 1) * 64, wn = (w >> 1) * 64;
    const size_t K = KBIG;

    const int sr = w * 16 + (lane >> 2);
    const int so = (lane & 3) * 8;
    const size_t zo = (size_t)z * 3200 + so;
    const unsigned short* gA0 = Ah + (size_t)(bm + sr) * K + zo;
    const unsigned short* gA1 = Ah + (size_t)(bm + 64 + sr) * K + zo;
    const unsigned short* ga0 = Al + (size_t)(bm + sr) * K + zo;
    const unsigned short* ga1 = Al + (size_t)(bm + 64 + sr) * K + zo;
    const unsigned short* gW0 = Wh + (size_t)(bn + sr) * K + zo;
    const unsigned short* gW1 = Wh + (size_t)(bn + 64 + sr) * K + zo;
    const unsigned short* gw0 = Wl + (size_t)(bn + sr) * K + zo;
    const unsigned short* gw1 = Wl + (size_t)(bn + 64 + sr) * K + zo;
    const int lb0 = w * 512, lb1 = 2048 + w * 512;

    v4f acc[4][4] = {};
    const int fr = lane & 15, fq = (lane >> 4) * 8;

#define STAGE_Z(buf, o)                                                        \
    gld16(gA0 + (o), &lds[buf][0][lb0]); gld16(gA1 + (o), &lds[buf][0][lb1]);  \
    gld16(ga0 + (o), &lds[buf][1][lb0]); gld16(ga1 + (o), &lds[buf][1][lb1]);  \
    gld16(gW0 + (o), &lds[buf][2][lb0]); gld16(gW1 + (o), &lds[buf][2][lb1]);  \
    gld16(gw0 + (o), &lds[buf][3][lb0]); gld16(gw1 + (o), &lds[buf][3][lb1]);

    STAGE_Z(0, 0);
    __syncthreads();
    int cur = 0;
    for (int kt = 0; kt < 100; ++kt) {
        if (kt < 99) { STAGE_Z(cur ^ 1, (kt + 1) * 32); }
        v8s ah[4], al[4], bh[4], bl[4];
        #pragma unroll
        for (int i = 0; i < 4; ++i) {
            ah[i] = *(const v8s*)&lds[cur][0][(wm + i * 16 + fr) * 32 + fq];
            al[i] = *(const v8s*)&lds[cur][1][(wm + i * 16 + fr) * 32 + fq];
            bh[i] = *(const v8s*)&lds[cur][2][(wn + i * 16 + fr) * 32 + fq];
            bl[i] = *(const v8s*)&lds[cur][3][(wn + i * 16 + fr) * 32 + fq];
        }
        #pragma unroll
        for (int mi = 0; mi < 4; ++mi)
            #pragma unroll
            for (int ni = 0; ni < 4; ++ni) {
                acc[mi][ni] = __builtin_amdgcn_mfma_f32_16x16x32_bf16(ah[mi], bh[ni], acc[mi][ni], 0, 0, 0);
                acc[mi][ni] = __builtin_amdgcn_mfma_f32_16x16x32_bf16(ah[mi], bl[ni], acc[mi][ni], 0, 0, 0);
                acc[mi][ni] = __builtin_amdgcn_mfma_f32_16x16x32_bf16(al[mi], bh[ni], acc[mi][ni], 0, 0, 0);
            }
        __syncthreads();
        cur ^= 1;
    }
#undef STAGE_Z

    const int er = (lane >> 4) * 4, ec = lane & 15;
    float* cp = part + (size_t)z * NBA * 512;
    #pragma unroll
    for (int mi = 0; mi < 4; ++mi)
        #pragma unroll
        for (int ni = 0; ni < 4; ++ni) {
            int m = bm + wm + mi * 16 + er;
            int n = bn + wn + ni * 16 + ec;
            #pragma unroll
            for (int r = 0; r < 4; ++r)
                cp[(size_t)(m + r) * 512 + n] = acc[mi][ni][r];
        }
}

// ---------------------------------------------------------------------------
// Split-K reduce + fold-bias + swish, emitting bf16 hi/lo directly.
// ---------------------------------------------------------------------------
__global__ __launch_bounds__(256) void k_g3red(
    const float* __restrict__ part, const float* __restrict__ comp_b1,
    const float* __restrict__ E0, const float* __restrict__ Corr,
    const int* __restrict__ nvalid,
    unsigned short* __restrict__ oh, unsigned short* __restrict__ ol)
{
    const int i4 = (blockIdx.x * 256 + threadIdx.x) * 4;
    const int ba = i4 >> 9, n = i4 & 511;
    const size_t S = (size_t)NBA * 512;
    float4 s = *(const float4*)(part + i4);
    #pragma unroll
    for (int zz = 1; zz < 8; ++zz) {
        float4 p = *(const float4*)(part + zz * S + i4);
        s.x += p.x; s.y += p.y; s.z += p.z; s.w += p.w;
    }
    int nv = nvalid[ba];
    float4 b  = *(const float4*)(comp_b1 + n);
    float4 e  = *(const float4*)(E0 + n);
    float4 c  = *(const float4*)(Corr + nv * 512 + n);
    float r0 = s.x + b.x + e.x + c.x;
    float r1 = s.y + b.y + e.y + c.y;
    float r2 = s.z + b.z + e.z + c.z;
    float r3 = s.w + b.w + e.w + c.w;
    float4 o;
    o.x = r0 / (1.0f + expf(-r0));
    o.y = r1 / (1.0f + expf(-r1));
    o.z = r2 / (1.0f + expf(-r2));
    o.w = r3 / (1.0f + expf(-r3));
    ushort4 h, l;
    h.x = bf_hi(o.x); l.x = bf_hi(o.x - bf_tof(h.x));
    h.y = bf_hi(o.y); l.y = bf_hi(o.y - bf_tof(h.y));
    h.z = bf_hi(o.z); l.z = bf_hi(o.z - bf_tof(h.z));
    h.w = bf_hi(o.w); l.w = bf_hi(o.w - bf_tof(h.w));
    *(ushort4*)(oh + i4) = h;
    *(ushort4*)(ol + i4) = l;
}

// ---------------------------------------------------------------------------
// Fused attention; emits swish(Hm) directly as bf16 hi/lo (feeds fp1 GEMM).
// ---------------------------------------------------------------------------
__global__ __launch_bounds__(256) void k_attn(
    const float* __restrict__ Qb, const float* __restrict__ Kb,
    const float* __restrict__ Vb, const float* __restrict__ conn,
    unsigned short* __restrict__ Oh, unsigned short* __restrict__ Ol)
{
    __shared__ float sKV[256][101];
    __shared__ float sAl[50][100];
    __shared__ float sQ[2][256];
    __shared__ float sRed[2][2];

    const int t = threadIdx.x;
    const int half = blockIdx.x, b = blockIdx.y, n = blockIdx.z;
    const size_t base = ((size_t)n * NBA + b * 100) * 256;

    const float* Kp = Kb + base;
    for (int r = 0; r < 100; ++r) sKV[t][r] = Kp[(size_t)r * 256 + t];
    __syncthreads();

    const float* Qp = Qb + base;
    const int pair = t >> 7, tt = t & 127, lane = t & 63, wvi = t >> 6;

    for (int rr = 0; rr < 25; ++rr) {
        const int row0 = half * 50 + rr * 2;
        const int lr = rr * 2 + pair;
        __syncthreads();
        sQ[0][t] = Qp[(size_t)(row0)*256 + t];
        sQ[1][t] = Qp[(size_t)(row0 + 1) * 256 + t];
        __syncthreads();
        float sc = 0.0f;
        if (tt < 100) {
            const float* qr = sQ[pair];
            float p0 = 0.f, p1 = 0.f, p2 = 0.f, p3 = 0.f;
            #pragma unroll 4
            for (int c = 0; c < 256; c += 4) {
                p0 += qr[c]     * sKV[c][tt];
                p1 += qr[c + 1] * sKV[c + 1][tt];
                p2 += qr[c + 2] * sKV[c + 2][tt];
                p3 += qr[c + 3] * sKV[c + 3][tt];
            }
            sc = ((p0 + p1) + (p2 + p3)) * 0.0625f + conn[(row0 + pair) * 100 + tt];
            sAl[lr][tt] = sc;
        }
        __syncthreads();
        if ((wvi & 1) == 0) {
            int p = wvi >> 1;
            int r2 = rr * 2 + p;
            float m = sAl[r2][lane];
            if (lane < 36) m = fmaxf(m, sAl[r2][lane + 64]);
            #pragma unroll
            for (int off = 32; off > 0; off >>= 1)
                m = fmaxf(m, __shfl_down(m, off));
            if (lane == 0) sRed[0][p] = m;
        }
        __syncthreads();
        float ex = 0.0f;
        if (tt < 100) {
            ex = expf(sc - sRed[0][pair]);
            sAl[lr][tt] = ex;
        }
        __syncthreads();
        if ((wvi & 1) == 0) {
            int p = wvi >> 1;
            int r2 = rr * 2 + p;
            float s = sAl[r2][lane];
            if (lane < 36) s += sAl[r2][lane + 64];
            #pragma unroll
            for (int off = 32; off > 0; off >>= 1)
                s += __shfl_down(s, off);
            if (lane == 0) sRed[1][p] = s;
        }
        __syncthreads();
        if (tt < 100) sAl[lr][tt] = ex / sRed[1][pair];
    }
    __syncthreads();

    const float* Vp = Vb + base;
    for (int r = 0; r < 100; ++r) sKV[t][r] = Vp[(size_t)r * 256 + t];
    __syncthreads();

    for (int rr = 0; rr < 50; ++rr) {
        int row = half * 50 + rr;
        float a = 0.0f;
        #pragma unroll 4
        for (int j = 0; j < 100; ++j) a += sAl[rr][j] * sKV[t][j];
        float sw = a / (1.0f + expf(-a));   // swish fused (fp1 consumes swish(Hm))
        size_t oidx = base + (size_t)row * 256 + t;
        unsigned short hv = bf_hi(sw);
        Oh[oidx] = hv;
        Ol[oidx] = bf_hi(sw - bf_tof(hv));
    }
}

// ---------------------------------------------------------------------------
// Per-head layernorm over HID + mean over heads -> new h (bf16 hi/lo).
// ---------------------------------------------------------------------------
__global__ __launch_bounds__(256) void k_ln_mean(
    const float* __restrict__ t2b, const float* __restrict__ ln_g,
    const float* __restrict__ ln_b,
    unsigned short* __restrict__ hh, unsigned short* __restrict__ hl)
{
    __shared__ float so[4][256];
    const int ba = blockIdx.x, t = threadIdx.x;
    const int n = t >> 6, lane = t & 63;
    const float* tr = t2b + ((size_t)n * NBA + ba) * HID;
    float4 v = *(const float4*)(tr + lane * 4);
    float s1 = v.x + v.y + v.z + v.w;
    float s2 = v.x * v.x + v.y * v.y + v.z * v.z + v.w * v.w;
    #pragma unroll
    for (int off = 32; off > 0; off >>= 1) {
        s1 += __shfl_down(s1, off);
        s2 += __shfl_down(s2, off);
    }
    s1 = __shfl(s1, 0);
    s2 = __shfl(s2, 0);
    float m = s1 * (1.0f / 256.0f);
    float var = s2 * (1.0f / 256.0f) - m * m;
    float rstd = 1.0f / sqrtf(var + 1e-5f);
    float4 gv = *(const float4*)(ln_g + n * HID + lane * 4);
    float4 bv = *(const float4*)(ln_b + n * HID + lane * 4);
    float4 o;
    o.x = (v.x - m) * rstd * gv.x + bv.x;
    o.y = (v.y - m) * rstd * gv.y + bv.y;
    o.z = (v.z - m) * rstd * gv.z + bv.z;
    o.w = (v.w - m) * rstd * gv.w + bv.w;
    *(float4*)&so[n][lane * 4] = o;
    __syncthreads();
    float hv = 0.25f * (so[0][t] + so[1][t] + so[2][t] + so[3][t]);
    unsigned short hi = bf_hi(hv);
    size_t oidx = (size_t)ba * HID + t;
    hh[oidx] = hi;
    hl[oidx] = bf_hi(hv - bf_tof(hi));
}

// ---------------------------------------------------------------------------
extern "C" void kernel_launch(void* const* d_in, const int* in_sizes, int n_in,
                              void* d_out, int out_size, void* d_ws, size_t ws_size,
                              hipStream_t stream)
{
    const float* x       = (const float*)d_in[0];
    const float* fourB   = (const float*)d_in[1];
    const float* enc_W1  = (const float*)d_in[2];
    const float* enc_b1  = (const float*)d_in[3];
    const float* enc_W2  = (const float*)d_in[4];
    const float* enc_b2  = (const float*)d_in[5];
    const float* pad_tok = (const float*)d_in[6];
    const float* comp_W1 = (const float*)d_in[7];
    const float* comp_b1 = (const float*)d_in[8];
    const float* comp_W2 = (const float*)d_in[9];
    const float* comp_b2 = (const float*)d_in[10];
    const float* conn    = (const float*)d_in[11];
    const float* qW      = (const float*)d_in[12];
    const float* kW      = (const float*)d_in[13];
    const float* vW      = (const float*)d_in[14];
    const float* fpW1    = (const float*)d_in[15];
    const float* fpb1    = (const float*)d_in[16];
    const float* fpW2    = (const float*)d_in[17];
    const float* fpb2    = (const float*)d_in[18];
    const float* ln_g    = (const float*)d_in[19];
    const float* ln_b    = (const float*)d_in[20];
    const float* out_W   = (const float*)d_in[21];
    const float* out_b   = (const float*)d_in[22];
    float* outp = (float*)d_out;

    // Workspace budget: 504,484,352 B (R4-proven; limit lies in (507.8, 517.6) MB)
    char* ws = (char*)d_ws;
    size_t off = 0;
    auto alloc = [&](size_t bytes) -> void* {
        void* p = (void*)(ws + off);
        off += (bytes + 255) & ~(size_t)255;
        return p;
    };
    int*   idxb = (int*)  alloc((size_t)NBA * EMAX * 4);
    float* valb = (float*)alloc((size_t)NBA * EMAX * 4);
    int*   nval = (int*)  alloc((size_t)NBA * 4);
    unsigned short* g1h = (unsigned short*)alloc((size_t)NBA * KBIG * 2);  // 163.8 MB
    unsigned short* g1l = (unsigned short*)alloc((size_t)NBA * KBIG * 2);  // 163.8 MB
    float* W2T  = (float*)alloc((size_t)256 * 256 * 4);
    float* W1p  = (float*)alloc((size_t)512 * KBIG * 4);     // 52.4 MB; reused as split-K partials
    float* part = W1p;                                       // alias (W1p dead after k_wsplit)
    unsigned short* Whi = (unsigned short*)alloc((size_t)512 * KBIG * 2);
    unsigned short* Wlo = (unsigned short*)alloc((size_t)512 * KBIG * 2);
    float* Dt   = (float*)alloc((size_t)100 * 512 * 4);
    float* Corr = (float*)alloc((size_t)101 * 512 * 4);
    float* E0   = (float*)alloc((size_t)512 * 4);
    // --- contiguous region: Qb | Kb | Vb | asplh | aspll ---
    // aliased earlier as cW1h/cW1l (bf16 split of comp_W1, dead after fold)
    float* Qb   = (float*)alloc((size_t)NHEAD * NBA * HID * 4);   // 13,107,200 B
    float* Kb   = (float*)alloc((size_t)NHEAD * NBA * HID * 4);
    float* Vb   = (float*)alloc((size_t)NHEAD * NBA * HID * 4);
    unsigned short* asplh = (unsigned short*)alloc((size_t)NHEAD * NBA * HID * 2); // 6.55 MB
    unsigned short* aspll = (unsigned short*)alloc((size_t)NHEAD * NBA * HID * 2);
    unsigned short* cW1h = (unsigned short*)Qb;   // spans Qb+Kb   (26.2 MB)
    unsigned short* cW1l = (unsigned short*)Vb;   // spans Vb+asplh+aspll (26.2 MB)
    // bspl: ALIAS into g1h (dead after k_g3mfma; bspl first written by the
    // comp_W2 GEMM which is strictly later in the stream).
    unsigned short* bsplh = g1h;
    unsigned short* bspll = g1h + (size_t)NHEAD * NBA * HID;
    // weight splits (persistent through the call)
    unsigned short* w2tH = (unsigned short*)alloc((size_t)256 * 256 * 2);
    unsigned short* w2tL = (unsigned short*)alloc((size_t)256 * 256 * 2);
    unsigned short* qkvWh = (unsigned short*)alloc((size_t)3 * NHEAD * HID * HID * 2);
    unsigned short* qkvWl = (unsigned short*)alloc((size_t)3 * NHEAD * HID * HID * 2);
    unsigned short* f1Wh = (unsigned short*)alloc((size_t)NHEAD * HID * HID * 2);
    unsigned short* f1Wl = (unsigned short*)alloc((size_t)NHEAD * HID * HID * 2);
    unsigned short* f2Wh = (unsigned short*)alloc((size_t)NHEAD * HID * HID * 2);
    unsigned short* f2Wl = (unsigned short*)alloc((size_t)NHEAD * HID * HID * 2);
    unsigned short* c2Wh = (unsigned short*)alloc((size_t)HID * 512 * 2);
    unsigned short* c2Wl = (unsigned short*)alloc((size_t)HID * 512 * 2);
    unsigned short* oWh  = (unsigned short*)alloc((size_t)NOUT * HID * 2);
    unsigned short* oWl  = (unsigned short*)alloc((size_t)NOUT * HID * 2);
    // aliases (lifetimes disjoint within a step)
    float* t2b  = Vb;   // V dead after attn

    const long long sW = (long long)HID * HID;   // 65536
    const long long sC = (long long)NBA * HID;   // 819200

    k_extract<<<NBA, 64, 0, stream>>>(x, idxb, valb, nval);
    k_g1<<<NBA * EMAX / 16, 256, 0, stream>>>(idxb, valb, nval, fourB,
                                              enc_W1, enc_b1, g1h, g1l);

    // fold enc_W2 into comp_W1 (split-bf16 MFMA)
    k_w2t<<<256, 256, 0, stream>>>(enc_W2, W2T);
    k_wsplit<<<256 * 256 / 1024, 256, 0, stream>>>(W2T, w2tH, w2tL);
    k_wsplit<<<512 * KBIG / 1024, 256, 0, stream>>>(comp_W1, cW1h, cW1l);
    k_gemmbf<0, 0><<<dim3(2, 400, 1), 256, 0, stream>>>(
        cW1h, cW1l, w2tH, w2tL, nullptr, W1p, nullptr, nullptr,
        512 * EMAX, 256, 256, 0, 0, 0, 0);
    k_wsplit<<<512 * KBIG / 1024, 256, 0, stream>>>(W1p, Whi, Wlo);
    k_tables<<<512, 256, 0, stream>>>(comp_W1, pad_tok, enc_b2, Dt, E0);
    k_suffix<<<2, 256, 0, stream>>>(Dt, Corr);

    // one-time weight splits
    k_wsplit<<<NHEAD * 65536 / 1024, 256, 0, stream>>>(qW, qkvWh, qkvWl);
    k_wsplit<<<NHEAD * 65536 / 1024, 256, 0, stream>>>(kW, qkvWh + NHEAD * 65536, qkvWl + NHEAD * 65536);
    k_wsplit<<<NHEAD * 65536 / 1024, 256, 0, stream>>>(vW, qkvWh + 2 * NHEAD * 65536, qkvWl + 2 * NHEAD * 65536);
    k_wsplit<<<NHEAD * 65536 / 1024, 256, 0, stream>>>(fpW1, f1Wh, f1Wl);
    k_wsplit<<<NHEAD * 65536 / 1024, 256, 0, stream>>>(fpW2, f2Wh, f2Wl);
    k_wsplit<<<HID * 512 / 1024, 256, 0, stream>>>(comp_W2, c2Wh, c2Wl);
    k_wsplit<<<NOUT * HID / 1024, 256, 0, stream>>>(out_W, oWh, oWl);

    // compression GEMM (M=3200,N=512,K=25600), split-K=8, XCD-swizzled 1D grid
    k_g3mfma<<<800, 256, 0, stream>>>(g1h, g1l, Whi, Wlo, part);
    // reduce + bias-fold + swish -> h1s split into aspl
    k_g3red<<<NBA * 512 / 1024, 256, 0, stream>>>(part, comp_b1, E0, Corr, nval, asplh, aspll);
    // h = h1s @ comp_W2^T + b2 -> split directly into bspl (g1h region, now dead)
    k_gemmbf<0, 1><<<dim3(2, 25, 1), 256, 0, stream>>>(
        asplh, aspll, c2Wh, c2Wl, comp_b2, nullptr, bsplh, bspll,
        NBA, HID, 512, 0, 0, 0, 0);

    for (int step = 0; step < 3; ++step) {
        // QKV: 12-batched, reads h-split (bspl), writes fp32 Q/K/V
        k_gemmbf<0, 0><<<dim3(2, 25, 12), 256, 0, stream>>>(
            bsplh, bspll, qkvWh, qkvWl, nullptr, Qb, nullptr, nullptr,
            NBA, HID, HID, 0, sW, 0, sC);
        // attn emits swish(Hm) split into aspl
        k_attn<<<dim3(2, NBATCH, NHEAD), 256, 0, stream>>>(Qb, Kb, Vb, conn, asplh, aspll);
        // fp1: swish epilogue + split out into bspl
        k_gemmbf<1, 1><<<dim3(2, 25, 4), 256, 0, stream>>>(
            asplh, aspll, f1Wh, f1Wl, fpb1, nullptr, bsplh, bspll,
            NBA, HID, HID, sC, sW, HID, sC);
        // fp2: fp32 out into t2b (=Vb, dead after attn)
        k_gemmbf<0, 0><<<dim3(2, 25, 4), 256, 0, stream>>>(
            bsplh, bspll, f2Wh, f2Wl, fpb2, t2b, nullptr, nullptr,
            NBA, HID, HID, sC, sW, HID, sC);
        // layernorm + head-mean -> next h split into bspl
        k_ln_mean<<<NBA, 256, 0, stream>>>(t2b, ln_g, ln_b, bsplh, bspll);
    }

    // out = h @ out_W^T + out_b  (M=3200, N=10000, K=256)
    k_gemmbf<0, 0><<<dim3(79, 25, 1), 256, 0, stream>>>(
        bsplh, bspll, oWh, oWl, out_b, outp, nullptr, nullptr,
        NBA, NOUT, HID, 0, 0, 0, 0);

    (void)in_sizes; (void)n_in; (void)out_size; (void)ws_size;
}

// Round 7
// 1792.744 us; speedup vs baseline: 1.4318x; 1.0180x over previous
//
#include <hip/hip_runtime.h>
#include <cstdint>
#include <cstddef>

#define NBATCH 32
#define NAGENT 100
#define NDIM   10000
#define HID    256
#define NHEAD  4
#define NOUT   10000
#define NFREQ  16
#define EMAX   100
#define NBA    3200                        // NBATCH * NAGENT
#define KBIG   25600                       // EMAX * HID
#define TWO_PI 6.283185307179586476925f

typedef float  v4f  __attribute__((ext_vector_type(4)));
typedef short  v8s  __attribute__((ext_vector_type(8)));

__device__ __forceinline__ unsigned short bf_hi(float f) {
    unsigned int u = __float_as_uint(f);
    return (unsigned short)((u + 0x7FFFu + ((u >> 16) & 1u)) >> 16);
}
__device__ __forceinline__ float bf_tof(unsigned short h) {
    return __uint_as_float(((unsigned int)h) << 16);
}

// async global->LDS, 16B per lane; LDS dest = wave-uniform base + lane*16
__device__ __forceinline__ void gld16(const void* g, void* l) {
    __builtin_amdgcn_global_load_lds(
        (const __attribute__((address_space(1))) void*)g,
        (__attribute__((address_space(3))) void*)l, 16, 0, 0);
}

// ---------------------------------------------------------------------------
// Stage 1: per-(b,a) stream compaction of nonzeros (ascending flat index),
// truncated to EMAX. One wave per (b,a). Matches stable argsort order.
// ---------------------------------------------------------------------------
__global__ __launch_bounds__(64) void k_extract(const float* __restrict__ x,
                                                int* __restrict__ idxb,
                                                float* __restrict__ valb,
                                                int* __restrict__ nvalid)
{
    const int ba = blockIdx.x;
    const float* xr = x + (size_t)ba * NDIM;
    const int lane = threadIdx.x;
    int base = 0;
    for (int c0 = 0; c0 < NDIM; c0 += 64) {
        int i = c0 + lane;
        float v = (i < NDIM) ? xr[i] : 0.0f;
        unsigned long long m = __ballot(v != 0.0f);
        if (v != 0.0f) {
            int p = base + __popcll(m & ((1ull << lane) - 1ull));
            if (p < EMAX) {
                idxb[(size_t)ba * EMAX + p] = i;
                valb[(size_t)ba * EMAX + p] = v;
            }
        }
        base += __popcll(m);
        if (base >= EMAX) break;           // uniform across wave
    }
    if (lane == 0) nvalid[ba] = base < EMAX ? base : EMAX;
}

// ---------------------------------------------------------------------------
// Stage 2: fourier + encoder layer-1. g1 = swish(feat @ enc_W1^T + b1).
// enc_W1 row held in 33 registers per thread; feat consumed as float4 LDS
// broadcasts (~180 in-loop LDS instr/thread vs ~1056 scalar).
// ---------------------------------------------------------------------------
__global__ __launch_bounds__(256) void k_g1(
    const int* __restrict__ idxb, const float* __restrict__ valb,
    const int* __restrict__ nvalid, const float* __restrict__ fourB,
    const float* __restrict__ W1, const float* __restrict__ b1,
    unsigned short* __restrict__ g1h, unsigned short* __restrict__ g1l)
{
    __shared__ float s_feat[16][36];       // row stride 144B (16B aligned)
    __shared__ float s_w[8448];            // enc_W1 256x33 (coalesced stage)
    __shared__ int   s_idx[16];
    __shared__ int   s_valid[16];

    const int t  = threadIdx.x;
    const int g0 = blockIdx.x * 16;

    if (t < 16) {
        int g = g0 + t;
        int ba = g / 100, slot = g - ba * 100;
        int valid = (slot < nvalid[ba]) ? 1 : 0;
        s_valid[t]   = valid;
        s_idx[t]     = valid ? idxb[g] : 0;
        s_feat[t][0] = valid ? valb[g] : 0.0f;
    }
    for (int i = t; i < 8448; i += 256) s_w[i] = W1[i];
    const float b1t = b1[t];
    __syncthreads();

    {   // Fourier features: 16 entries x 16 freqs = 256 work items
        int ent = t >> 4, f = t & 15;
        float sv = 0.0f, cv = 0.0f;
        if (s_valid[ent]) {
            int id = s_idx[ent];
            float row = (float)(id / 100);
            float col = (float)(id % 100);
            float pr = TWO_PI * (row * fourB[2 * f] + col * fourB[2 * f + 1]);
            sv = sinf(pr); cv = cosf(pr);
        }
        s_feat[ent][1 + f]  = sv;
        s_feat[ent][17 + f] = cv;
    }
    __syncthreads();

    float wreg[33];                        // thread-private enc_W1 row
    #pragma unroll
    for (int c = 0; c < 33; ++c) wreg[c] = s_w[t * 33 + c];

    for (int ent = 0; ent < 16; ++ent) {
        const float* fr_ = &s_feat[ent][0];
        float a = b1t;
        #pragma unroll
        for (int c4 = 0; c4 < 8; ++c4) {
            float4 f = *(const float4*)(fr_ + c4 * 4);
            a += f.x * wreg[c4 * 4] + f.y * wreg[c4 * 4 + 1]
               + f.z * wreg[c4 * 4 + 2] + f.w * wreg[c4 * 4 + 3];
        }
        a += fr_[32] * wreg[32];
        float g = a / (1.0f + expf(-a));   // swish
        g = s_valid[ent] ? g : 0.0f;
        unsigned short h = bf_hi(g);
        unsigned short l = bf_hi(g - bf_tof(h));
        size_t o = (size_t)(g0 + ent) * 256 + t;
        g1h[o] = h;
        g1l[o] = l;
    }
}

// ---------------------------------------------------------------------------
// W2T split: w2t{H,L}[kp][k] = split(W2[k][kp])  (fused transpose + split)
// ---------------------------------------------------------------------------
__global__ void k_w2t(const float* __restrict__ W2,
                      unsigned short* __restrict__ w2tH,
                      unsigned short* __restrict__ w2tL)
{
    int kp = blockIdx.x, k = threadIdx.x;
    float v = W2[k * 256 + kp];
    unsigned short h = bf_hi(v);
    w2tH[kp * 256 + k] = h;
    w2tL[kp * 256 + k] = bf_hi(v - bf_tof(h));
}

// ---------------------------------------------------------------------------
// fp32 -> bf16 hi/lo elementwise split (generic; total elems = grid*1024)
// ---------------------------------------------------------------------------
__global__ __launch_bounds__(256) void k_wsplit(const float* __restrict__ src,
                                                unsigned short* __restrict__ hi,
                                                unsigned short* __restrict__ lo)
{
    int i = (blockIdx.x * 256 + threadIdx.x) * 4;
    float4 f = *(const float4*)(src + i);
    ushort4 h, l;
    h.x = bf_hi(f.x); l.x = bf_hi(f.x - bf_tof(h.x));
    h.y = bf_hi(f.y); l.y = bf_hi(f.y - bf_tof(h.y));
    h.z = bf_hi(f.z); l.z = bf_hi(f.z - bf_tof(h.z));
    h.w = bf_hi(f.w); l.w = bf_hi(f.w - bf_tof(h.w));
    *(ushort4*)(hi + i) = h;
    *(ushort4*)(lo + i) = l;
}

// ---------------------------------------------------------------------------
// All one-time weight splits fused into a single dispatch (7 -> 1).
// ---------------------------------------------------------------------------
__global__ __launch_bounds__(256) void k_wsplit_all(
    const float* __restrict__ qW, const float* __restrict__ kW,
    const float* __restrict__ vW, const float* __restrict__ fpW1,
    const float* __restrict__ fpW2, const float* __restrict__ comp_W2,
    const float* __restrict__ out_W,
    unsigned short* __restrict__ qkvWh, unsigned short* __restrict__ qkvWl,
    unsigned short* __restrict__ f1Wh, unsigned short* __restrict__ f1Wl,
    unsigned short* __restrict__ f2Wh, unsigned short* __restrict__ f2Wl,
    unsigned short* __restrict__ c2Wh, unsigned short* __restrict__ c2Wl,
    unsigned short* __restrict__ oWh, unsigned short* __restrict__ oWl)
{
    const int b = blockIdx.x;
    const float* src; unsigned short* hi; unsigned short* lo; int rel;
    if (b < 256)        { src = qW;      hi = qkvWh;          lo = qkvWl;          rel = b; }
    else if (b < 512)   { src = kW;      hi = qkvWh + 262144; lo = qkvWl + 262144; rel = b - 256; }
    else if (b < 768)   { src = vW;      hi = qkvWh + 524288; lo = qkvWl + 524288; rel = b - 512; }
    else if (b < 1024)  { src = fpW1;    hi = f1Wh;           lo = f1Wl;           rel = b - 768; }
    else if (b < 1280)  { src = fpW2;    hi = f2Wh;           lo = f2Wl;           rel = b - 1024; }
    else if (b < 1408)  { src = comp_W2; hi = c2Wh;           lo = c2Wl;           rel = b - 1280; }
    else                { src = out_W;   hi = oWh;            lo = oWl;            rel = b - 1408; }
    int i = (rel * 256 + threadIdx.x) * 4;
    float4 f = *(const float4*)(src + i);
    ushort4 h, l;
    h.x = bf_hi(f.x); l.x = bf_hi(f.x - bf_tof(h.x));
    h.y = bf_hi(f.y); l.y = bf_hi(f.y - bf_tof(h.y));
    h.z = bf_hi(f.z); l.z = bf_hi(f.z - bf_tof(h.z));
    h.w = bf_hi(f.w); l.w = bf_hi(f.w - bf_tof(h.w));
    *(ushort4*)(hi + i) = h;
    *(ushort4*)(lo + i) = l;
}

// ---------------------------------------------------------------------------
// Bias tables for the W2-fold: wave-per-s (stride 4), float4 coalesced,
// no in-loop barriers.
// ---------------------------------------------------------------------------
__global__ __launch_bounds__(256) void k_tables(
    const float* __restrict__ W1, const float* __restrict__ pad,
    const float* __restrict__ b2, float* __restrict__ D, float* __restrict__ E0)
{
    __shared__ float red[4];
    const int n = blockIdx.x;
    const int t = threadIdx.x, lane = t & 63, w = t >> 6;
    float4 pd = *(const float4*)(pad + lane * 4);
    float4 b4 = *(const float4*)(b2 + lane * 4);
    float4 pm4 = make_float4(pd.x - b4.x, pd.y - b4.y, pd.z - b4.z, pd.w - b4.w);
    const float* wr = W1 + (size_t)n * KBIG;
    float eb = 0.0f;
    for (int s = w; s < 100; s += 4) {
        float4 wv = *(const float4*)(wr + s * 256 + lane * 4);
        float p = pm4.x * wv.x + pm4.y * wv.y + pm4.z * wv.z + pm4.w * wv.w;
        eb += b4.x * wv.x + b4.y * wv.y + b4.z * wv.z + b4.w * wv.w;
        #pragma unroll
        for (int o = 32; o > 0; o >>= 1) p += __shfl_down(p, o);
        if (lane == 0) D[s * 512 + n] = p;
    }
    #pragma unroll
    for (int o = 32; o > 0; o >>= 1) eb += __shfl_down(eb, o);
    if (lane == 0) red[w] = eb;
    __syncthreads();
    if (t == 0) E0[n] = red[0] + red[1] + red[2] + red[3];
}

__global__ void k_suffix(const float* __restrict__ D, float* __restrict__ Corr)
{
    int n = blockIdx.x * 256 + threadIdx.x;   // 512 columns
    float c = 0.0f;
    Corr[100 * 512 + n] = 0.0f;
    for (int s = 99; s >= 0; --s) { c += D[s * 512 + n]; Corr[s * 512 + n] = c; }
}

// ---------------------------------------------------------------------------
// Generic split-bf16 MFMA GEMM (R5-verified body, unchanged): C = act(A@W^T
// + bias) via hi/lo compensation (3 MFMAs). 128x128 tile, BK=32, gld_lds
// double-buffered staging, ONE __syncthreads per K-step. W rows clamped for
// OOB tiles; clamped columns never written (n<N guard).
// SPLIT=1: emit bf16 hi/lo (Ch/Cl) instead of fp32 C.
// ---------------------------------------------------------------------------
template<int ACT, int SPLIT>
__global__ __launch_bounds__(256) void k_gemmbf(
    const unsigned short* __restrict__ Ah, const unsigned short* __restrict__ Al,
    const unsigned short* __restrict__ Wh, const unsigned short* __restrict__ Wl,
    const float* __restrict__ bias, float* __restrict__ C,
    unsigned short* __restrict__ Ch, unsigned short* __restrict__ Cl,
    int M, int N, int K,
    long long sA, long long sW, long long sBias, long long sC)
{
    __shared__ unsigned short lds[2][4][4096];   // [buf][Ah,Al,Wh,Wl][128 rows x 32]
    const int t = threadIdx.x;
    const int z = blockIdx.z;
    Ah += (size_t)z * sA;  Al += (size_t)z * sA;
    Wh += (size_t)z * sW;  Wl += (size_t)z * sW;
    if (SPLIT) { Ch += (size_t)z * sC; Cl += (size_t)z * sC; }
    else       { C  += (size_t)z * sC; }
    const float* bp = bias ? (bias + (size_t)z * sBias) : nullptr;
    const int bn = blockIdx.x * 128, bm = blockIdx.y * 128;
    const int lane = t & 63, w = t >> 6;
    const int wm = (w & 1) * 64, wn = (w >> 1) * 64;

    const int sr = w * 16 + (lane >> 2);
    const int so = (lane & 3) * 8;
    int rw0 = bn + sr;       if (rw0 >= N) rw0 = N - 1;   // clamp OOB W rows
    int rw1 = bn + 64 + sr;  if (rw1 >= N) rw1 = N - 1;
    const unsigned short* gA0 = Ah + (size_t)(bm + sr) * K + so;
    const unsigned short* gA1 = Ah + (size_t)(bm + 64 + sr) * K + so;
    const unsigned short* ga0 = Al + (size_t)(bm + sr) * K + so;
    const unsigned short* ga1 = Al + (size_t)(bm + 64 + sr) * K + so;
    const unsigned short* gW0 = Wh + (size_t)rw0 * K + so;
    const unsigned short* gW1 = Wh + (size_t)rw1 * K + so;
    const unsigned short* gw0 = Wl + (size_t)rw0 * K + so;
    const unsigned short* gw1 = Wl + (size_t)rw1 * K + so;
    const int lb0 = w * 512;          // ushort offset of wave chunk, half 0
    const int lb1 = 2048 + w * 512;   // half 1

    v4f acc[4][4] = {};
    const int fr = lane & 15, fq = (lane >> 4) * 8;
    const int KT = K >> 5;

#define STAGE_G(buf, o)                                                        \
    gld16(gA0 + (o), &lds[buf][0][lb0]); gld16(gA1 + (o), &lds[buf][0][lb1]);  \
    gld16(ga0 + (o), &lds[buf][1][lb0]); gld16(ga1 + (o), &lds[buf][1][lb1]);  \
    gld16(gW0 + (o), &lds[buf][2][lb0]); gld16(gW1 + (o), &lds[buf][2][lb1]);  \
    gld16(gw0 + (o), &lds[buf][3][lb0]); gld16(gw1 + (o), &lds[buf][3][lb1]);

    STAGE_G(0, 0);
    __syncthreads();                   // drains vmcnt: buf0 ready
    int cur = 0;
    for (int kt = 0; kt < KT; ++kt) {
        if (kt + 1 < KT) { STAGE_G(cur ^ 1, (kt + 1) * 32); }
        v8s ahf[4], alf[4], bhf[4], blf[4];
        #pragma unroll
        for (int i = 0; i < 4; ++i) {
            ahf[i] = *(const v8s*)&lds[cur][0][(wm + i * 16 + fr) * 32 + fq];
            alf[i] = *(const v8s*)&lds[cur][1][(wm + i * 16 + fr) * 32 + fq];
            bhf[i] = *(const v8s*)&lds[cur][2][(wn + i * 16 + fr) * 32 + fq];
            blf[i] = *(const v8s*)&lds[cur][3][(wn + i * 16 + fr) * 32 + fq];
        }
        #pragma unroll
        for (int mi = 0; mi < 4; ++mi)
            #pragma unroll
            for (int ni = 0; ni < 4; ++ni) {
                acc[mi][ni] = __builtin_amdgcn_mfma_f32_16x16x32_bf16(ahf[mi], bhf[ni], acc[mi][ni], 0, 0, 0);
                acc[mi][ni] = __builtin_amdgcn_mfma_f32_16x16x32_bf16(ahf[mi], blf[ni], acc[mi][ni], 0, 0, 0);
                acc[mi][ni] = __builtin_amdgcn_mfma_f32_16x16x32_bf16(alf[mi], bhf[ni], acc[mi][ni], 0, 0, 0);
            }
        __syncthreads();               // drains next-tile DMA + all LDS reads
        cur ^= 1;
    }
#undef STAGE_G

    const int er = (lane >> 4) * 4, ec = lane & 15;  // C/D: col=lane&15, row=quad*4+reg
    #pragma unroll
    for (int mi = 0; mi < 4; ++mi)
        #pragma unroll
        for (int ni = 0; ni < 4; ++ni) {
            int m = bm + wm + mi * 16 + er;
            int n = bn + wn + ni * 16 + ec;
            if (n < N) {
                float bv = bp ? bp[n] : 0.0f;
                #pragma unroll
                for (int r = 0; r < 4; ++r) {
                    float val = acc[mi][ni][r] + bv;
                    if (ACT == 1) val = val / (1.0f + expf(-val));   // swish
                    if (SPLIT) {
                        unsigned short hv = bf_hi(val);
                        Ch[(size_t)(m + r) * N + n] = hv;
                        Cl[(size_t)(m + r) * N + n] = bf_hi(val - bf_tof(hv));
                    } else {
                        C[(size_t)(m + r) * N + n] = val;
                    }
                }
            }
        }
    (void)M;
}

// ---------------------------------------------------------------------------
// Compression GEMM via bf16 MFMA hi/lo split, split-K=8 (R5-verified body).
// XCD-swizzled 1D grid + gld_lds dbuf staging, one __syncthreads per K-step.
// ---------------------------------------------------------------------------
__global__ __launch_bounds__(256) void k_g3mfma(
    const unsigned short* __restrict__ Ah, const unsigned short* __restrict__ Al,
    const unsigned short* __restrict__ Wh, const unsigned short* __restrict__ Wl,
    float* __restrict__ part)
{
    __shared__ unsigned short lds[2][4][4096];
    const int t  = threadIdx.x;
    // XCD swizzle: hw block h -> work wk = (h%8)*100 + h/8  (800 = 8*100, bijective)
    const int hwid = blockIdx.x;
    const int wk = (hwid & 7) * 100 + (hwid >> 3);
    const int bn = (wk & 3) * 128;         // N in [0,512)
    const int bm = ((wk >> 2) % 25) * 128; // M in [0,3200)
    const int z  = wk / 100;               // split-K chunk (== hwid%8)
    const int lane = t & 63, w = t >> 6;
    const int wm = (w & 1) * 64, wn = (w >> 1) * 64;
    const size_t K = KBIG;

    const int sr = w * 16 + (lane >> 2);
    const int so = (lane & 3) * 8;
    const size_t zo = (size_t)z * 3200 + so;
    const unsigned short* gA0 = Ah + (size_t)(bm + sr) * K + zo;
    const unsigned short* gA1 = Ah + (size_t)(bm + 64 + sr) * K + zo;
    const unsigned short* ga0 = Al + (size_t)(bm + sr) * K + zo;
    const unsigned short* ga1 = Al + (size_t)(bm + 64 + sr) * K + zo;
    const unsigned short* gW0 = Wh + (size_t)(bn + sr) * K + zo;
    const unsigned short* gW1 = Wh + (size_t)(bn + 64 + sr) * K + zo;
    const unsigned short* gw0 = Wl + (size_t)(bn + sr) * K + zo;
    const unsigned short* gw1 = Wl + (size_t)(bn + 64 + sr) * K + zo;
    const int lb0 = w * 512, lb1 = 2048 + w * 512;

    v4f acc[4][4] = {};
    const int fr = lane & 15, fq = (lane >> 4) * 8;

#define STAGE_Z(buf, o)                                                        \
    gld16(gA0 + (o), &lds[buf][0][lb0]); gld16(gA1 + (o), &lds[buf][0][lb1]);  \
    gld16(ga0 + (o), &lds[buf][1][lb0]); gld16(ga1 + (o), &lds[buf][1][lb1]);  \
    gld16(gW0 + (o), &lds[buf][2][lb0]); gld16(gW1 + (o), &lds[buf][2][lb1]);  \
    gld16(gw0 + (o), &lds[buf][3][lb0]); gld16(gw1 + (o), &lds[buf][3][lb1]);

    STAGE_Z(0, 0);
    __syncthreads();
    int cur = 0;
    for (int kt = 0; kt < 100; ++kt) {
        if (kt < 99) { STAGE_Z(cur ^ 1, (kt + 1) * 32); }
        v8s ah[4], al[4], bh[4], bl[4];
        #pragma unroll
        for (int i = 0; i < 4; ++i) {
            ah[i] = *(const v8s*)&lds[cur][0][(wm + i * 16 + fr) * 32 + fq];
            al[i] = *(const v8s*)&lds[cur][1][(wm + i * 16 + fr) * 32 + fq];
            bh[i] = *(const v8s*)&lds[cur][2][(wn + i * 16 + fr) * 32 + fq];
            bl[i] = *(const v8s*)&lds[cur][3][(wn + i * 16 + fr) * 32 + fq];
        }
        #pragma unroll
        for (int mi = 0; mi < 4; ++mi)
            #pragma unroll
            for (int ni = 0; ni < 4; ++ni) {
                acc[mi][ni] = __builtin_amdgcn_mfma_f32_16x16x32_bf16(ah[mi], bh[ni], acc[mi][ni], 0, 0, 0);
                acc[mi][ni] = __builtin_amdgcn_mfma_f32_16x16x32_bf16(ah[mi], bl[ni], acc[mi][ni], 0, 0, 0);
                acc[mi][ni] = __builtin_amdgcn_mfma_f32_16x16x32_bf16(al[mi], bh[ni], acc[mi][ni], 0, 0, 0);
            }
        __syncthreads();
        cur ^= 1;
    }
#undef STAGE_Z

    const int er = (lane >> 4) * 4, ec = lane & 15;
    float* cp = part + (size_t)z * NBA * 512;
    #pragma unroll
    for (int mi = 0; mi < 4; ++mi)
        #pragma unroll
        for (int ni = 0; ni < 4; ++ni) {
            int m = bm + wm + mi * 16 + er;
            int n = bn + wn + ni * 16 + ec;
            #pragma unroll
            for (int r = 0; r < 4; ++r)
                cp[(size_t)(m + r) * 512 + n] = acc[mi][ni][r];
        }
}

// ---------------------------------------------------------------------------
// Split-K reduce + fold-bias + swish, emitting bf16 hi/lo directly.
// ---------------------------------------------------------------------------
__global__ __launch_bounds__(256) void k_g3red(
    const float* __restrict__ part, const float* __restrict__ comp_b1,
    const float* __restrict__ E0, const float* __restrict__ Corr,
    const int* __restrict__ nvalid,
    unsigned short* __restrict__ oh, unsigned short* __restrict__ ol)
{
    const int i4 = (blockIdx.x * 256 + threadIdx.x) * 4;
    const int ba = i4 >> 9, n = i4 & 511;
    const size_t S = (size_t)NBA * 512;
    float4 s = *(const float4*)(part + i4);
    #pragma unroll
    for (int zz = 1; zz < 8; ++zz) {
        float4 p = *(const float4*)(part + zz * S + i4);
        s.x += p.x; s.y += p.y; s.z += p.z; s.w += p.w;
    }
    int nv = nvalid[ba];
    float4 b  = *(const float4*)(comp_b1 + n);
    float4 e  = *(const float4*)(E0 + n);
    float4 c  = *(const float4*)(Corr + nv * 512 + n);
    float r0 = s.x + b.x + e.x + c.x;
    float r1 = s.y + b.y + e.y + c.y;
    float r2 = s.z + b.z + e.z + c.z;
    float r3 = s.w + b.w + e.w + c.w;
    float4 o;
    o.x = r0 / (1.0f + expf(-r0));
    o.y = r1 / (1.0f + expf(-r1));
    o.z = r2 / (1.0f + expf(-r2));
    o.w = r3 / (1.0f + expf(-r3));
    ushort4 h, l;
    h.x = bf_hi(o.x); l.x = bf_hi(o.x - bf_tof(h.x));
    h.y = bf_hi(o.y); l.y = bf_hi(o.y - bf_tof(h.y));
    h.z = bf_hi(o.z); l.z = bf_hi(o.z - bf_tof(h.z));
    h.w = bf_hi(o.w); l.w = bf_hi(o.w - bf_tof(h.w));
    *(ushort4*)(oh + i4) = h;
    *(ushort4*)(ol + i4) = l;
}

// ---------------------------------------------------------------------------
// Fused attention; emits swish(Hm) directly as bf16 hi/lo (feeds fp1 GEMM).
// ---------------------------------------------------------------------------
__global__ __launch_bounds__(256) void k_attn(
    const float* __restrict__ Qb, const float* __restrict__ Kb,
    const float* __restrict__ Vb, const float* __restrict__ conn,
    unsigned short* __restrict__ Oh, unsigned short* __restrict__ Ol)
{
    __shared__ float sKV[256][101];
    __shared__ float sAl[50][100];
    __shared__ float sQ[2][256];
    __shared__ float sRed[2][2];

    const int t = threadIdx.x;
    const int half = blockIdx.x, b = blockIdx.y, n = blockIdx.z;
    const size_t base = ((size_t)n * NBA + b * 100) * 256;

    const float* Kp = Kb + base;
    for (int r = 0; r < 100; ++r) sKV[t][r] = Kp[(size_t)r * 256 + t];
    __syncthreads();

    const float* Qp = Qb + base;
    const int pair = t >> 7, tt = t & 127, lane = t & 63, wvi = t >> 6;

    for (int rr = 0; rr < 25; ++rr) {
        const int row0 = half * 50 + rr * 2;
        const int lr = rr * 2 + pair;
        __syncthreads();
        sQ[0][t] = Qp[(size_t)(row0)*256 + t];
        sQ[1][t] = Qp[(size_t)(row0 + 1) * 256 + t];
        __syncthreads();
        float sc = 0.0f;
        if (tt < 100) {
            const float* qr = sQ[pair];
            float p0 = 0.f, p1 = 0.f, p2 = 0.f, p3 = 0.f;
            #pragma unroll 4
            for (int c = 0; c < 256; c += 4) {
                p0 += qr[c]     * sKV[c][tt];
                p1 += qr[c + 1] * sKV[c + 1][tt];
                p2 += qr[c + 2] * sKV[c + 2][tt];
                p3 += qr[c + 3] * sKV[c + 3][tt];
            }
            sc = ((p0 + p1) + (p2 + p3)) * 0.0625f + conn[(row0 + pair) * 100 + tt];
            sAl[lr][tt] = sc;
        }
        __syncthreads();
        if ((wvi & 1) == 0) {
            int p = wvi >> 1;
            int r2 = rr * 2 + p;
            float m = sAl[r2][lane];
            if (lane < 36) m = fmaxf(m, sAl[r2][lane + 64]);
            #pragma unroll
            for (int off = 32; off > 0; off >>= 1)
                m = fmaxf(m, __shfl_down(m, off));
            if (lane == 0) sRed[0][p] = m;
        }
        __syncthreads();
        float ex = 0.0f;
        if (tt < 100) {
            ex = expf(sc - sRed[0][pair]);
            sAl[lr][tt] = ex;
        }
        __syncthreads();
        if ((wvi & 1) == 0) {
            int p = wvi >> 1;
            int r2 = rr * 2 + p;
            float s = sAl[r2][lane];
            if (lane < 36) s += sAl[r2][lane + 64];
            #pragma unroll
            for (int off = 32; off > 0; off >>= 1)
                s += __shfl_down(s, off);
            if (lane == 0) sRed[1][p] = s;
        }
        __syncthreads();
        if (tt < 100) sAl[lr][tt] = ex / sRed[1][pair];
    }
    __syncthreads();

    const float* Vp = Vb + base;
    for (int r = 0; r < 100; ++r) sKV[t][r] = Vp[(size_t)r * 256 + t];
    __syncthreads();

    for (int rr = 0; rr < 50; ++rr) {
        int row = half * 50 + rr;
        float a = 0.0f;
        #pragma unroll 4
        for (int j = 0; j < 100; ++j) a += sAl[rr][j] * sKV[t][j];
        float sw = a / (1.0f + expf(-a));   // swish fused (fp1 consumes swish(Hm))
        size_t oidx = base + (size_t)row * 256 + t;
        unsigned short hv = bf_hi(sw);
        Oh[oidx] = hv;
        Ol[oidx] = bf_hi(sw - bf_tof(hv));
    }
}

// ---------------------------------------------------------------------------
// Per-head layernorm over HID + mean over heads -> new h (bf16 hi/lo).
// ---------------------------------------------------------------------------
__global__ __launch_bounds__(256) void k_ln_mean(
    const float* __restrict__ t2b, const float* __restrict__ ln_g,
    const float* __restrict__ ln_b,
    unsigned short* __restrict__ hh, unsigned short* __restrict__ hl)
{
    __shared__ float so[4][256];
    const int ba = blockIdx.x, t = threadIdx.x;
    const int n = t >> 6, lane = t & 63;
    const float* tr = t2b + ((size_t)n * NBA + ba) * HID;
    float4 v = *(const float4*)(tr + lane * 4);
    float s1 = v.x + v.y + v.z + v.w;
    float s2 = v.x * v.x + v.y * v.y + v.z * v.z + v.w * v.w;
    #pragma unroll
    for (int off = 32; off > 0; off >>= 1) {
        s1 += __shfl_down(s1, off);
        s2 += __shfl_down(s2, off);
    }
    s1 = __shfl(s1, 0);
    s2 = __shfl(s2, 0);
    float m = s1 * (1.0f / 256.0f);
    float var = s2 * (1.0f / 256.0f) - m * m;
    float rstd = 1.0f / sqrtf(var + 1e-5f);
    float4 gv = *(const float4*)(ln_g + n * HID + lane * 4);
    float4 bv = *(const float4*)(ln_b + n * HID + lane * 4);
    float4 o;
    o.x = (v.x - m) * rstd * gv.x + bv.x;
    o.y = (v.y - m) * rstd * gv.y + bv.y;
    o.z = (v.z - m) * rstd * gv.z + bv.z;
    o.w = (v.w - m) * rstd * gv.w + bv.w;
    *(float4*)&so[n][lane * 4] = o;
    __syncthreads();
    float hv = 0.25f * (so[0][t] + so[1][t] + so[2][t] + so[3][t]);
    unsigned short hi = bf_hi(hv);
    size_t oidx = (size_t)ba * HID + t;
    hh[oidx] = hi;
    hl[oidx] = bf_hi(hv - bf_tof(hi));
}

// ---------------------------------------------------------------------------
extern "C" void kernel_launch(void* const* d_in, const int* in_sizes, int n_in,
                              void* d_out, int out_size, void* d_ws, size_t ws_size,
                              hipStream_t stream)
{
    const float* x       = (const float*)d_in[0];
    const float* fourB   = (const float*)d_in[1];
    const float* enc_W1  = (const float*)d_in[2];
    const float* enc_b1  = (const float*)d_in[3];
    const float* enc_W2  = (const float*)d_in[4];
    const float* enc_b2  = (const float*)d_in[5];
    const float* pad_tok = (const float*)d_in[6];
    const float* comp_W1 = (const float*)d_in[7];
    const float* comp_b1 = (const float*)d_in[8];
    const float* comp_W2 = (const float*)d_in[9];
    const float* comp_b2 = (const float*)d_in[10];
    const float* conn    = (const float*)d_in[11];
    const float* qW      = (const float*)d_in[12];
    const float* kW      = (const float*)d_in[13];
    const float* vW      = (const float*)d_in[14];
    const float* fpW1    = (const float*)d_in[15];
    const float* fpb1    = (const float*)d_in[16];
    const float* fpW2    = (const float*)d_in[17];
    const float* fpb2    = (const float*)d_in[18];
    const float* ln_g    = (const float*)d_in[19];
    const float* ln_b    = (const float*)d_in[20];
    const float* out_W   = (const float*)d_in[21];
    const float* out_b   = (const float*)d_in[22];
    float* outp = (float*)d_out;

    // Workspace total: ~451.8 MB (< 504.5 MB proven bound).
    char* ws = (char*)d_ws;
    size_t off = 0;
    auto alloc = [&](size_t bytes) -> void* {
        void* p = (void*)(ws + off);
        off += (bytes + 255) & ~(size_t)255;
        return p;
    };
    int*   idxb = (int*)  alloc((size_t)NBA * EMAX * 4);
    float* valb = (float*)alloc((size_t)NBA * EMAX * 4);
    int*   nval = (int*)  alloc((size_t)NBA * 4);
    unsigned short* g1h = (unsigned short*)alloc((size_t)NBA * KBIG * 2);  // 163.8 MB
    unsigned short* g1l = (unsigned short*)alloc((size_t)NBA * KBIG * 2);  // 163.8 MB
    unsigned short* Whi = (unsigned short*)alloc((size_t)512 * KBIG * 2);  // 26.2 MB
    unsigned short* Wlo = (unsigned short*)alloc((size_t)512 * KBIG * 2);
    float* Dt   = (float*)alloc((size_t)100 * 512 * 4);
    float* Corr = (float*)alloc((size_t)101 * 512 * 4);
    float* E0   = (float*)alloc((size_t)512 * 4);
    // --- contiguous region: Qb | Kb | Vb | asplh | aspll  (52.4 MB) ---
    // t0: cW1h spans Qb+Kb, cW1l spans Vb+asplh+aspll (fold inputs)
    // t1: part (split-K partials, 8 x 6.55 MB) spans the whole region
    // t2: Qb/Kb/Vb + attn-output aspl (loop phase; part dead after g3red)
    float* Qb   = (float*)alloc((size_t)NHEAD * NBA * HID * 4);   // 13,107,200 B
    float* Kb   = (float*)alloc((size_t)NHEAD * NBA * HID * 4);
    float* Vb   = (float*)alloc((size_t)NHEAD * NBA * HID * 4);
    unsigned short* asplh = (unsigned short*)alloc((size_t)NHEAD * NBA * HID * 2); // 6.55 MB
    unsigned short* aspll = (unsigned short*)alloc((size_t)NHEAD * NBA * HID * 2);
    unsigned short* cW1h = (unsigned short*)Qb;   // 26.2 MB (Qb+Kb)
    unsigned short* cW1l = (unsigned short*)Vb;   // 26.2 MB (Vb+asplh+aspll)
    float* part = Qb;                              // 52.4 MB (whole region)
    // h1s / bspl in the dead g1h region.  R7 FIX: bspl buffers are written by
    // fp1 with FOUR z-slices (sC = NBA*HID) -> each needs NHEAD*NBA*HID room.
    // R6 spaced them NBA*HID apart -> fp1 head-slices 1-3 overwrote bspll
    // (the 4.26e-3 failure).  Layout (ushort offsets into g1h):
    //   h1sh [0, 1.64M) | h1sl [1.64M, 3.28M) | bsplh [3.28M, 6.55M) |
    //   bspll [6.55M, 9.83M)  -- all < 81.9M (g1h extent), all 16B-aligned.
    unsigned short* h1sh  = g1h;                          // NBA*512
    unsigned short* h1sl  = g1h + (size_t)NBA * 512;
    unsigned short* bsplh = g1h + (size_t)2 * NBA * 512;  // NHEAD*NBA*HID room
    unsigned short* bspll = bsplh + (size_t)NHEAD * NBA * HID;
    // weight splits (persistent through the call)
    unsigned short* w2tH = (unsigned short*)alloc((size_t)256 * 256 * 2);
    unsigned short* w2tL = (unsigned short*)alloc((size_t)256 * 256 * 2);
    unsigned short* qkvWh = (unsigned short*)alloc((size_t)3 * NHEAD * HID * HID * 2);
    unsigned short* qkvWl = (unsigned short*)alloc((size_t)3 * NHEAD * HID * HID * 2);
    unsigned short* f1Wh = (unsigned short*)alloc((size_t)NHEAD * HID * HID * 2);
    unsigned short* f1Wl = (unsigned short*)alloc((size_t)NHEAD * HID * HID * 2);
    unsigned short* f2Wh = (unsigned short*)alloc((size_t)NHEAD * HID * HID * 2);
    unsigned short* f2Wl = (unsigned short*)alloc((size_t)NHEAD * HID * HID * 2);
    unsigned short* c2Wh = (unsigned short*)alloc((size_t)HID * 512 * 2);
    unsigned short* c2Wl = (unsigned short*)alloc((size_t)HID * 512 * 2);
    unsigned short* oWh  = (unsigned short*)alloc((size_t)NOUT * HID * 2);
    unsigned short* oWl  = (unsigned short*)alloc((size_t)NOUT * HID * 2);
    // aliases (lifetimes disjoint within a step)
    float* t2b  = Vb;   // V dead after attn

    const long long sW = (long long)HID * HID;   // 65536
    const long long sC = (long long)NBA * HID;   // 819200

    k_extract<<<NBA, 64, 0, stream>>>(x, idxb, valb, nval);
    k_g1<<<NBA * EMAX / 16, 256, 0, stream>>>(idxb, valb, nval, fourB,
                                              enc_W1, enc_b1, g1h, g1l);

    // fold enc_W2 into comp_W1 (split-bf16 MFMA), emitting Whi/Wlo directly
    k_w2t<<<256, 256, 0, stream>>>(enc_W2, w2tH, w2tL);
    k_wsplit<<<512 * KBIG / 1024, 256, 0, stream>>>(comp_W1, cW1h, cW1l);
    k_gemmbf<0, 1><<<dim3(2, 400, 1), 256, 0, stream>>>(
        cW1h, cW1l, w2tH, w2tL, nullptr, nullptr, Whi, Wlo,
        512 * EMAX, 256, 256, 0, 0, 0, 0);
    k_tables<<<512, 256, 0, stream>>>(comp_W1, pad_tok, enc_b2, Dt, E0);
    k_suffix<<<2, 256, 0, stream>>>(Dt, Corr);

    // all one-time weight splits in a single dispatch
    k_wsplit_all<<<3908, 256, 0, stream>>>(
        qW, kW, vW, fpW1, fpW2, comp_W2, out_W,
        qkvWh, qkvWl, f1Wh, f1Wl, f2Wh, f2Wl, c2Wh, c2Wl, oWh, oWl);

    // compression GEMM (M=3200,N=512,K=25600), split-K=8, XCD-swizzled 1D grid
    k_g3mfma<<<800, 256, 0, stream>>>(g1h, g1l, Whi, Wlo, part);
    // reduce + bias-fold + swish -> h1s split (g1h region; g1 now dead)
    k_g3red<<<NBA * 512 / 1024, 256, 0, stream>>>(part, comp_b1, E0, Corr, nval, h1sh, h1sl);
    // h = h1s @ comp_W2^T + b2 -> split directly into bspl (slice 0 only)
    k_gemmbf<0, 1><<<dim3(2, 25, 1), 256, 0, stream>>>(
        h1sh, h1sl, c2Wh, c2Wl, comp_b2, nullptr, bsplh, bspll,
        NBA, HID, 512, 0, 0, 0, 0);

    for (int step = 0; step < 3; ++step) {
        // QKV: 12-batched, reads h-split (bspl slice 0), writes fp32 Q/K/V
        k_gemmbf<0, 0><<<dim3(2, 25, 12), 256, 0, stream>>>(
            bsplh, bspll, qkvWh, qkvWl, nullptr, Qb, nullptr, nullptr,
            NBA, HID, HID, 0, sW, 0, sC);
        // attn emits swish(Hm) split into aspl
        k_attn<<<dim3(2, NBATCH, NHEAD), 256, 0, stream>>>(Qb, Kb, Vb, conn, asplh, aspll);
        // fp1: swish epilogue + split out into bspl (4 head-slices)
        k_gemmbf<1, 1><<<dim3(2, 25, 4), 256, 0, stream>>>(
            asplh, aspll, f1Wh, f1Wl, fpb1, nullptr, bsplh, bspll,
            NBA, HID, HID, sC, sW, HID, sC);
        // fp2: fp32 out into t2b (=Vb, dead after attn)
        k_gemmbf<0, 0><<<dim3(2, 25, 4), 256, 0, stream>>>(
            bsplh, bspll, f2Wh, f2Wl, fpb2, t2b, nullptr, nullptr,
            NBA, HID, HID, sC, sW, HID, sC);
        // layernorm + head-mean -> next h split into bspl slice 0
        k_ln_mean<<<NBA, 256, 0, stream>>>(t2b, ln_g, ln_b, bsplh, bspll);
    }

    // out = h @ out_W^T + out_b  (M=3200, N=10000, K=256)
    k_gemmbf<0, 0><<<dim3(79, 25, 1), 256, 0, stream>>>(
        bsplh, bspll, oWh, oWl, out_b, outp, nullptr, nullptr,
        NBA, NOUT, HID, 0, 0, 0, 0);

    (void)in_sizes; (void)n_in; (void)out_size; (void)ws_size;
}